// Round 6
// baseline (1893.652 us; speedup 1.0000x reference)
//
#include <hip/hip_runtime.h>
#include <hip/hip_bf16.h>
#include <math.h>

// Problem constants
constexpr int Bz  = 32;
constexpr int S   = 197;
constexpr int E   = 256;
constexpr int Hn  = 16;
constexpr int HD  = 16;
constexpr int Fd  = 3072;
constexpr int Ln  = 12;
constexpr int MS  = Bz * S;         // 6304 tokens
constexpr int MP  = 6400;           // padded to 50 * 128 for MFMA GEMM tiles
constexpr int NPAT = 6272;          // 32*196 patches = 49*128 exactly
constexpr int DVL = 50, DVR = 49, DVT = 49;

typedef __attribute__((ext_vector_type(8))) short short8;   // 8 bf16 = 4 VGPRs
typedef __attribute__((ext_vector_type(4))) short short4v;
typedef __attribute__((ext_vector_type(4))) float f32x4;

__device__ __forceinline__ unsigned short f2bf(float f) {
    unsigned int u = __float_as_uint(f);
    u = (u + 0x7FFFu + ((u >> 16) & 1u)) >> 16;             // RNE
    return (unsigned short)u;
}

// async global->LDS, 16 B per lane. LDS dest is wave-uniform base + lane*16.
__device__ __forceinline__ void gload_lds16(const void* g, void* l) {
    __builtin_amdgcn_global_load_lds(
        (const __attribute__((address_space(1))) void*)g,
        (__attribute__((address_space(3))) void*)l, 16, 0, 0);
}

// wave reduce (64 lanes), op 0=sum 1=max
__device__ __forceinline__ float wave_reduce(float v, int op) {
    #pragma unroll
    for (int off = 32; off > 0; off >>= 1) {
        float o = __shfl_xor(v, off, 64);
        v = op ? fmaxf(v, o) : v + o;
    }
    return v;
}

// block-wide reduce (256 thr): wave shuffle + 4-slot LDS. op: 0=sum, 1=max.
__device__ __forceinline__ float block_reduce(float v, float* red4, int op) {
    v = wave_reduce(v, op);
    int w = threadIdx.x >> 6;
    if ((threadIdx.x & 63) == 0) red4[w] = v;
    __syncthreads();
    float r = op ? fmaxf(fmaxf(red4[0], red4[1]), fmaxf(red4[2], red4[3]))
                 : (red4[0] + red4[1] + red4[2] + red4[3]);
    __syncthreads();
    return r;
}

// ---------------------------------------------------------------------------
// Patchify: x (B,1,224,224) -> bf16 A[6272][256], A[b*196+q][pr*16+pc].
__global__ __launch_bounds__(256) void patchify_kernel(
        const float* __restrict__ x, unsigned short* __restrict__ Ab) {
    int pi = blockIdx.x;                 // 0..6271
    int b = pi / 196, q = pi % 196;
    int i = q / 14, j = q % 14;
    int e = threadIdx.x, pr = e >> 4, pc = e & 15;
    float v = x[((size_t)(b * 224 + i * 16 + pr)) * 224 + j * 16 + pc];
    Ab[(size_t)pi * 256 + e] = f2bf(v);
}

// cls token rows of h0
__global__ __launch_bounds__(256) void cls_pos_kernel(
        const float* __restrict__ cls, const float* __restrict__ pos,
        float* __restrict__ h0) {
    int b = blockIdx.x, e = threadIdx.x;
    h0[(size_t)(b * S) * E + e] = cls[e] + pos[e];
}

// fp32 -> bf16, 4 elems/thread
__global__ __launch_bounds__(256) void convert_kernel(
        const float* __restrict__ src, unsigned short* __restrict__ dst) {
    int i4 = (blockIdx.x * 256 + threadIdx.x) * 4;
    float4 v = *(const float4*)(src + i4);
    ushort4 o;
    o.x = f2bf(v.x); o.y = f2bf(v.y); o.z = f2bf(v.z); o.w = f2bf(v.w);
    *(ushort4*)(dst + i4) = o;
}

// ---------------------------------------------------------------------------
// rag stage 1: per-sample token means. grid 32, 256 thr, coalesced.
__global__ __launch_bounds__(256) void means_kernel(
        const float* __restrict__ h0, float* __restrict__ M) {
    int b = blockIdx.x, e = threadIdx.x;
    float s = 0.f;
    for (int t = 0; t < S; t++) s += h0[((size_t)(b * S + t)) * E + e];
    M[b * E + e] = s * (1.f / (float)S);
}

// rag stage 2: U_x[t] = Wk_x.T @ M[t], c_x[t] = bk_x . M[t]. grid 32.
__global__ __launch_bounds__(256) void uvec_kernel(
        const float* __restrict__ M,
        const float* __restrict__ Wkl, const float* __restrict__ bkl,
        const float* __restrict__ Wkr, const float* __restrict__ bkr,
        const float* __restrict__ Wkt, const float* __restrict__ bkt,
        float* __restrict__ Ul, float* __restrict__ Ur, float* __restrict__ Ut,
        float* __restrict__ cl, float* __restrict__ cr, float* __restrict__ ct) {
    __shared__ float red4[4];
    int t = blockIdx.x, e = threadIdx.x;
    const float* mt = M + t * E;
    float a0 = 0.f, a1 = 0.f, a2 = 0.f;
    for (int i = 0; i < 256; i++) {
        float mi = mt[i];                       // wave-uniform -> s_load
        a0 += Wkl[(size_t)i * 256 + e] * mi;
        a1 += Wkr[(size_t)i * 256 + e] * mi;
        a2 += Wkt[(size_t)i * 256 + e] * mi;
    }
    Ul[t * E + e] = a0; Ur[t * E + e] = a1; Ut[t * E + e] = a2;
    float me = mt[e];
    float c0 = block_reduce(bkl[e] * me, red4, 0);
    float c1 = block_reduce(bkr[e] * me, red4, 0);
    float c2 = block_reduce(bkt[e] * me, red4, 0);
    if (e == 0) { cl[t] = c0; cr[t] = c1; ct[t] = c2; }
}

// rag stage 3: scores+softmax+xbar+f for one (t, branch). grid 120, 256 thr.
__global__ __launch_bounds__(256) void rag_score_kernel(
        const float* __restrict__ h0, const float* __restrict__ M,
        const float* __restrict__ Ul, const float* __restrict__ Ur,
        const float* __restrict__ Ut,
        const float* __restrict__ cl, const float* __restrict__ cr,
        const float* __restrict__ ct,
        const float* __restrict__ Wvl, const float* __restrict__ bvl,
        const float* __restrict__ Wvr, const float* __restrict__ bvr,
        const float* __restrict__ Wvt, const float* __restrict__ bvt,
        float* __restrict__ fbuf) {
    int t = blockIdx.x >> 2, br = blockIdx.x & 3;
    const float* xsrc; const float* u; float c;
    const float* Wv; const float* bv; int dv, fo;
    if (br == 0)      { xsrc = h0 + (size_t)t * S * E;       u = Ul + (t+1)*E; c = cl[t+1]; Wv = Wvl; bv = bvl; dv = DVL; fo = 0; }
    else if (br == 1) { xsrc = h0 + (size_t)(t+1) * S * E;   u = Ut + t*E;     c = ct[t];   Wv = Wvt; bv = bvt; dv = DVT; fo = DVL; }
    else if (br == 2) { xsrc = h0 + (size_t)(t+1) * S * E;   u = Ut + (t+2)*E; c = ct[t+2]; Wv = Wvt; bv = bvt; dv = DVT; fo = DVL + DVT; }
    else              { xsrc = h0 + (size_t)(t+2) * S * E;   u = Ur + (t+1)*E; c = cr[t+1]; Wv = Wvr; bv = bvr; dv = DVR; fo = DVL + 2*DVT; }
    __shared__ float us[256], sc[200], xbar[256], red4[4];
    int tid = threadIdx.x, w = tid >> 6, lane = tid & 63;
    us[tid] = u[tid];
    __syncthreads();
    float4 u4 = *(float4*)&us[lane * 4];
    for (int s = w; s < S; s += 4) {
        float4 x4 = *(const float4*)&xsrc[(size_t)s * E + lane * 4];
        float p = x4.x*u4.x + x4.y*u4.y + x4.z*u4.z + x4.w*u4.w;
        p = wave_reduce(p, 0);
        if (lane == 0) sc[s] = (p + c) * 0.0625f;     // 1/sqrt(E)
    }
    __syncthreads();
    float v = (tid < S) ? sc[tid] : -1e30f;
    float mx = block_reduce(v, red4, 1);
    float ex = (tid < S) ? expf(v - mx) : 0.f;
    float dn = block_reduce(ex, red4, 0);
    if (tid < S) sc[tid] = ex / dn;
    __syncthreads();
    float xb = 0.f;
    for (int s = 0; s < S; s++) xb += sc[s] * xsrc[(size_t)s * E + tid];
    xbar[tid] = xb;
    __syncthreads();
    float4 xb4 = *(float4*)&xbar[lane * 4];
    for (int d = w; d < dv; d += 4) {
        float4 w4 = *(const float4*)&Wv[(size_t)d * E + lane * 4];
        float p = w4.x*xb4.x + w4.y*xb4.y + w4.z*xb4.z + w4.w*xb4.w;
        p = wave_reduce(p, 0);
        if (lane == 0) fbuf[t * 256 + fo + d] = p + bv[d];
    }
}

// rag stage 4: outer product h1[t+1][s][:] = f[t][s] * M[t+1][:]
__global__ __launch_bounds__(256) void rag_outer_kernel(
        const float* __restrict__ fbuf, const float* __restrict__ M,
        float* __restrict__ h1) {
    int bid = blockIdx.x;                    // 0..30*197-1
    int t = bid / S, s = bid % S;
    float f = fbuf[t * 256 + s];             // uniform
    int e = threadIdx.x;
    h1[((size_t)((t + 1) * S + s)) * E + e] = f * M[(t + 1) * E + e];
}

// copy h0 samples 0 and 31 into h1
__global__ __launch_bounds__(256) void copy_edges(const float* __restrict__ h0,
                                                  float* __restrict__ h1) {
    int i = blockIdx.x * 256 + threadIdx.x;
    int n = S * E;
    if (i < n) h1[i] = h0[i];
    else if (i < 2 * n) {
        int j = i - n;
        size_t o = (size_t)31 * S * E + j;
        h1[o] = h0[o];
    }
}

// ---------------------------------------------------------------------------
// LayerNorm over E=256: wave per token, float4, shuffle-only. grid MS/4.
__global__ __launch_bounds__(256) void ln_kernel(const float* __restrict__ in,
                                                 unsigned short* __restrict__ out,
                                                 const float* __restrict__ g,
                                                 const float* __restrict__ b) {
    int w = threadIdx.x >> 6, lane = threadIdx.x & 63;
    int tok = blockIdx.x * 4 + w;
    const float* row = in + (size_t)tok * E;
    float4 v = *(const float4*)&row[lane * 4];
    float mean = wave_reduce(v.x + v.y + v.z + v.w, 0) * (1.f / 256.f);
    float dx = v.x - mean, dy = v.y - mean, dz = v.z - mean, dw = v.w - mean;
    float var = wave_reduce(dx*dx + dy*dy + dz*dz + dw*dw, 0) * (1.f / 256.f);
    float inv = rsqrtf(var + 1e-5f);
    float4 gg = *(const float4*)&g[lane * 4];
    float4 bb = *(const float4*)&b[lane * 4];
    ushort4 o;
    o.x = f2bf(dx * inv * gg.x + bb.x);
    o.y = f2bf(dy * inv * gg.y + bb.y);
    o.z = f2bf(dz * inv * gg.z + bb.z);
    o.w = f2bf(dw * inv * gg.w + bb.w);
    *(ushort4*)&out[(size_t)tok * E + lane * 4] = o;
}

// ---------------------------------------------------------------------------
// Per-layer weight conversion fp32 -> bf16 into staging buffer.
__global__ __launch_bounds__(256) void convert_w_kernel(
        const float* __restrict__ wqkv, const float* __restrict__ wo,
        const float* __restrict__ w1, const float* __restrict__ w2,
        unsigned short* __restrict__ out) {
    int idx = blockIdx.x * 256 + threadIdx.x;       // 0..458751
    int i4 = idx * 4;
    const float* src;
    if (i4 < 196608)       src = wqkv + i4;
    else if (i4 < 262144)  src = wo + (i4 - 196608);
    else if (i4 < 1048576) src = w1 + (i4 - 262144);
    else                   src = w2 + (i4 - 1048576);
    float4 v = *(const float4*)src;
    ushort4 o;
    o.x = f2bf(v.x); o.y = f2bf(v.y); o.z = f2bf(v.z); o.w = f2bf(v.w);
    *(ushort4*)(out + i4) = o;
}

// ---------------------------------------------------------------------------
// bf16 MFMA GEMM, 128x128 tile, BK=64, global_load_lds staging, XOR-swizzled
// LDS. MODE 0: fp32 store (+bias) | MODE 2: gelu -> bf16 | MODE 4: bf16 store
template <int MODE>
__global__ __launch_bounds__(256) void mfma_gemm(
        const unsigned short* __restrict__ A, int lda,
        const unsigned short* __restrict__ W, int ldw,
        const float* __restrict__ bias,
        void* __restrict__ Cv, int ldc, int K) {
    __shared__ unsigned short As[128 * 64];
    __shared__ unsigned short Bs[128 * 64];
    const int m0 = blockIdx.y * 128, n0 = blockIdx.x * 128;
    const int tid = threadIdx.x, wave = tid >> 6, lane = tid & 63;
    const int wm = (wave >> 1) * 64, wn = (wave & 1) * 64;
    const int lr = lane & 15, kg = lane >> 4;
    const int srow = wave * 32 + (lane >> 3);           // +q*8
    const int scol = ((lane & 7) ^ (lane >> 3)) * 8;    // swizzled granule col
    f32x4 acc[4][4] = {};
    for (int k0 = 0; k0 < K; k0 += 64) {
        #pragma unroll
        for (int q = 0; q < 4; q++) {
            gload_lds16(&A[(size_t)(m0 + srow + q * 8) * lda + k0 + scol],
                        &As[(wave * 4 + q) * 512]);
            gload_lds16(&W[(size_t)(n0 + srow + q * 8) * ldw + k0 + scol],
                        &Bs[(wave * 4 + q) * 512]);
        }
        __syncthreads();
        #pragma unroll
        for (int h = 0; h < 2; h++) {
            const int sw = ((h * 4 + kg) ^ (lr & 7)) * 8;
            short8 af[4], bfr[4];
            #pragma unroll
            for (int i = 0; i < 4; i++) af[i]  = *(short8*)&As[(wm + i * 16 + lr) * 64 + sw];
            #pragma unroll
            for (int j = 0; j < 4; j++) bfr[j] = *(short8*)&Bs[(wn + j * 16 + lr) * 64 + sw];
            #pragma unroll
            for (int i = 0; i < 4; i++)
                #pragma unroll
                for (int j = 0; j < 4; j++)
                    acc[i][j] = __builtin_amdgcn_mfma_f32_16x16x32_bf16(af[i], bfr[j], acc[i][j], 0, 0, 0);
        }
        __syncthreads();
    }
    #pragma unroll
    for (int j = 0; j < 4; j++) {
        int n = n0 + wn + j * 16 + lr;
        float bv = bias ? bias[n] : 0.f;
        #pragma unroll
        for (int i = 0; i < 4; i++) {
            #pragma unroll
            for (int r = 0; r < 4; r++) {
                size_t m = (size_t)(m0 + wm + i * 16 + kg * 4 + r);
                float v = acc[i][j][r] + bv;
                if (MODE == 0) ((float*)Cv)[m * ldc + n] = v;
                if (MODE == 2) {
                    v = 0.5f * v * (1.f + erff(v * 0.70710678118654752f));
                    ((unsigned short*)Cv)[m * ldc + n] = f2bf(v);
                }
                if (MODE == 4) ((unsigned short*)Cv)[m * ldc + n] = f2bf(v);
            }
        }
    }
}

// ---------------------------------------------------------------------------
// bf16 MFMA GEMM, 128x64 tile, BK=64, same staging/swizzle. 4 waves x (32x64).
// MODE 1: fp32 += (+bias) | MODE 3: patch-embed epilogue (token remap + pos)
template <int MODE>
__global__ __launch_bounds__(256) void mfma_gemm64(
        const unsigned short* __restrict__ A, int lda,
        const unsigned short* __restrict__ W, int ldw,
        const float* __restrict__ bias,
        void* __restrict__ Cv, int ldc, int K,
        const float* __restrict__ pos) {
    __shared__ unsigned short As[128 * 64];
    __shared__ unsigned short Bs[64 * 64];
    const int m0 = blockIdx.y * 128, n0 = blockIdx.x * 64;
    const int tid = threadIdx.x, wave = tid >> 6, lane = tid & 63;
    const int wm = wave * 32;
    const int lr = lane & 15, kg = lane >> 4;
    const int srow = wave * 32 + (lane >> 3);
    const int brow = wave * 16 + (lane >> 3);
    const int scol = ((lane & 7) ^ (lane >> 3)) * 8;
    f32x4 acc[2][4] = {};
    for (int k0 = 0; k0 < K; k0 += 64) {
        #pragma unroll
        for (int q = 0; q < 4; q++)
            gload_lds16(&A[(size_t)(m0 + srow + q * 8) * lda + k0 + scol],
                        &As[(wave * 4 + q) * 512]);
        #pragma unroll
        for (int q = 0; q < 2; q++)
            gload_lds16(&W[(size_t)(n0 + brow + q * 8) * ldw + k0 + scol],
                        &Bs[(wave * 2 + q) * 512]);
        __syncthreads();
        #pragma unroll
        for (int h = 0; h < 2; h++) {
            const int sw = ((h * 4 + kg) ^ (lr & 7)) * 8;
            short8 af[2], bfr[4];
            #pragma unroll
            for (int i = 0; i < 2; i++) af[i]  = *(short8*)&As[(wm + i * 16 + lr) * 64 + sw];
            #pragma unroll
            for (int j = 0; j < 4; j++) bfr[j] = *(short8*)&Bs[(j * 16 + lr) * 64 + sw];
            #pragma unroll
            for (int i = 0; i < 2; i++)
                #pragma unroll
                for (int j = 0; j < 4; j++)
                    acc[i][j] = __builtin_amdgcn_mfma_f32_16x16x32_bf16(af[i], bfr[j], acc[i][j], 0, 0, 0);
        }
        __syncthreads();
    }
    #pragma unroll
    for (int j = 0; j < 4; j++) {
        int n = n0 + j * 16 + lr;
        float bv = bias ? bias[n] : 0.f;
        #pragma unroll
        for (int i = 0; i < 2; i++) {
            #pragma unroll
            for (int r = 0; r < 4; r++) {
                int m = m0 + wm + i * 16 + kg * 4 + r;
                float v = acc[i][j][r] + bv;
                if (MODE == 1) ((float*)Cv)[(size_t)m * ldc + n] += v;
                if (MODE == 3) {
                    int b = m / 196, s = m - b * 196 + 1;   // token remap
                    ((float*)Cv)[((size_t)(b * S + s)) * E + n] = v + pos[(size_t)s * E + n];
                }
            }
        }
    }
}

// ---------------------------------------------------------------------------
// Split-K bf16 MFMA GEMM for N=256 outputs: C[M,256] += A[M,K]@W[256,K]^T
// (+bias, added by k-chunk 0 only). BM=64, BN=256 (full N -> A read ONCE),
// BK=64. grid (SK, M/64). 4 waves; wave w owns n in [w*64,(w+1)*64).
// Epilogue: native fp32 atomic add into C (residual already in C).
__global__ __launch_bounds__(256) void mfma_gemm_sk(
        const unsigned short* __restrict__ A, int lda,
        const unsigned short* __restrict__ W, int ldw,
        const float* __restrict__ bias,
        float* __restrict__ C, int ldc, int K, int SK) {
    __shared__ unsigned short As[64 * 64];
    __shared__ unsigned short Bs[256 * 64];
    const int KC = K / SK;
    const int m0 = blockIdx.y * 64, kbase = blockIdx.x * KC;
    const int tid = threadIdx.x, wave = tid >> 6, lane = tid & 63;
    const int lr = lane & 15, kg = lane >> 4;
    const int rq = lane >> 3;                           // row-in-8-group
    const int scol = ((lane & 7) ^ rq) * 8;             // swizzled granule col
    f32x4 acc[4][4] = {};
    for (int k0 = kbase; k0 < kbase + KC; k0 += 64) {
        #pragma unroll
        for (int q = 0; q < 2; q++)
            gload_lds16(&A[(size_t)(m0 + wave * 16 + q * 8 + rq) * lda + k0 + scol],
                        &As[(wave * 16 + q * 8) * 64]);
        #pragma unroll
        for (int q = 0; q < 8; q++)
            gload_lds16(&W[(size_t)(wave * 64 + q * 8 + rq) * ldw + k0 + scol],
                        &Bs[(wave * 64 + q * 8) * 64]);
        __syncthreads();
        #pragma unroll
        for (int h = 0; h < 2; h++) {
            const int sw = ((h * 4 + kg) ^ (lr & 7)) * 8;
            short8 af[4], bfr[4];
            #pragma unroll
            for (int i = 0; i < 4; i++) af[i]  = *(short8*)&As[(i * 16 + lr) * 64 + sw];
            #pragma unroll
            for (int j = 0; j < 4; j++) bfr[j] = *(short8*)&Bs[(wave * 64 + j * 16 + lr) * 64 + sw];
            #pragma unroll
            for (int i = 0; i < 4; i++)
                #pragma unroll
                for (int j = 0; j < 4; j++)
                    acc[i][j] = __builtin_amdgcn_mfma_f32_16x16x32_bf16(af[i], bfr[j], acc[i][j], 0, 0, 0);
        }
        __syncthreads();
    }
    const bool addb = (blockIdx.x == 0) && bias;
    #pragma unroll
    for (int j = 0; j < 4; j++) {
        int n = wave * 64 + j * 16 + lr;
        float bv = addb ? bias[n] : 0.f;
        #pragma unroll
        for (int i = 0; i < 4; i++) {
            #pragma unroll
            for (int r = 0; r < 4; r++) {
                int m = m0 + i * 16 + kg * 4 + r;
                unsafeAtomicAdd(&C[(size_t)m * ldc + n], acc[i][j][r] + bv);
            }
        }
    }
}

// ---------------------------------------------------------------------------
// MFMA flash attention. One block per (b,h); 4 waves, each takes Q-tiles
// round-robin. qkv bf16 [MS][768]; out bf16 [MS][256].
__global__ __launch_bounds__(256) void attn_kernel(
        const unsigned short* __restrict__ qkv, unsigned short* __restrict__ o) {
    int b = blockIdx.x >> 4, hh = blockIdx.x & 15;
    __shared__ unsigned short Qs[208][32];
    __shared__ unsigned short Ks[208][32];
    __shared__ unsigned short Vt[16][224];
    __shared__ unsigned short Ps[4][16][224];
    int tid = threadIdx.x, wave = tid >> 6, lane = tid & 63;
    int lr = lane & 15, kg = lane >> 4;
    short8 z8 = {};
    if (tid < 208) {
        if (tid < 197) {
            size_t row = (size_t)(b * S + tid) * 768 + hh * 16;
            *(short8*)&Qs[tid][0] = *(const short8*)&qkv[row];
            *(short8*)&Qs[tid][8] = *(const short8*)&qkv[row + 8];
            *(short8*)&Ks[tid][0] = *(const short8*)&qkv[row + 256];
            *(short8*)&Ks[tid][8] = *(const short8*)&qkv[row + 264];
            union { short8 v8[2]; unsigned short u[16]; } vv;
            vv.v8[0] = *(const short8*)&qkv[row + 512];
            vv.v8[1] = *(const short8*)&qkv[row + 520];
            #pragma unroll
            for (int d = 0; d < 16; d++) Vt[d][tid] = vv.u[d];
        } else {
            *(short8*)&Qs[tid][0] = z8; *(short8*)&Qs[tid][8] = z8;
            *(short8*)&Ks[tid][0] = z8; *(short8*)&Ks[tid][8] = z8;
            #pragma unroll
            for (int d = 0; d < 16; d++) Vt[d][tid] = 0;
        }
        *(short8*)&Qs[tid][16] = z8; *(short8*)&Qs[tid][24] = z8;
        *(short8*)&Ks[tid][16] = z8; *(short8*)&Ks[tid][24] = z8;
    } else if (tid < 224) {
        #pragma unroll
        for (int d = 0; d < 16; d++) Vt[d][tid] = 0;
    }
    {   // zero P pad cols [208,224) of this wave's scratch
        short4v z4 = {};
        *(short4v*)&Ps[wave][lane >> 2][208 + (lane & 3) * 4] = z4;
    }
    __syncthreads();
    const f32x4 zf = {0.f, 0.f, 0.f, 0.f};
    for (int it = wave; it < 13; it += 4) {
        short8 qa = *(short8*)&Qs[it * 16 + lr][kg * 8];
        f32x4 sc[13];
        #pragma unroll
        for (int j = 0; j < 13; j++) {
            short8 kb = *(short8*)&Ks[j * 16 + lr][kg * 8];
            sc[j] = __builtin_amdgcn_mfma_f32_16x16x32_bf16(qa, kb, zf, 0, 0, 0);
        }
        float m[4] = {-1e30f, -1e30f, -1e30f, -1e30f};
        #pragma unroll
        for (int j = 0; j < 13; j++) {
            if (j * 16 + lr < 197) {
                #pragma unroll
                for (int r = 0; r < 4; r++) m[r] = fmaxf(m[r], sc[j][r]);
            }
        }
        #pragma unroll
        for (int off = 1; off < 16; off <<= 1)
            #pragma unroll
            for (int r = 0; r < 4; r++) m[r] = fmaxf(m[r], __shfl_xor(m[r], off, 64));
        float l[4] = {0.f, 0.f, 0.f, 0.f};
        #pragma unroll
        for (int j = 0; j < 13; j++) {
            bool valid = (j * 16 + lr) < 197;
            #pragma unroll
            for (int r = 0; r < 4; r++) {
                float p = valid ? __expf((sc[j][r] - m[r]) * 0.25f) : 0.f;
                l[r] += p;
                Ps[wave][kg * 4 + r][j * 16 + lr] = f2bf(p);
            }
        }
        #pragma unroll
        for (int off = 1; off < 16; off <<= 1)
            #pragma unroll
            for (int r = 0; r < 4; r++) l[r] += __shfl_xor(l[r], off, 64);
        f32x4 oa = zf;
        #pragma unroll
        for (int k0 = 0; k0 < 224; k0 += 32) {
            short8 pa = *(short8*)&Ps[wave][lr][k0 + kg * 8];
            short8 vb = *(short8*)&Vt[lr][k0 + kg * 8];
            oa = __builtin_amdgcn_mfma_f32_16x16x32_bf16(pa, vb, oa, 0, 0, 0);
        }
        #pragma unroll
        for (int r = 0; r < 4; r++) {
            int q = it * 16 + kg * 4 + r;
            if (q < 197)
                o[((size_t)(b * S + q)) * 256 + hh * 16 + lr] = f2bf(oa[r] / l[r]);
        }
    }
}

// ---------------------------------------------------------------------------
// Final LN on cls token + head GEMM. One block per sample.
__global__ __launch_bounds__(256) void head_kernel(
        const float* __restrict__ h, const float* __restrict__ g,
        const float* __restrict__ bb, const float* __restrict__ Wh,
        const float* __restrict__ bh, float* __restrict__ out) {
    __shared__ float red4[4];
    __shared__ float xs[256];
    int b = blockIdx.x, e = threadIdx.x;
    float v = h[((size_t)(b * S)) * E + e];
    float mean = block_reduce(v, red4, 0) * (1.f / 256.f);
    float d = v - mean;
    float var = block_reduce(d * d, red4, 0) * (1.f / 256.f);
    float xn = d * rsqrtf(var + 1e-5f) * g[e] + bb[e];
    xs[e] = xn;
    __syncthreads();
    for (int n = 0; n < 8; n++) {
        float s = block_reduce(xs[e] * Wh[(size_t)n * 256 + e], red4, 0);
        if (e == 0) out[b * 8 + n] = s + bh[n];
    }
}

// ---------------------------------------------------------------------------
extern "C" void kernel_launch(void* const* d_in, const int* in_sizes, int n_in,
                              void* d_out, int out_size, void* d_ws, size_t ws_size,
                              hipStream_t stream) {
    const float* x      = (const float*)d_in[0];
    const float* W_patch= (const float*)d_in[1];
    const float* b_patch= (const float*)d_in[2];
    const float* cls_tok= (const float*)d_in[3];
    const float* pos_emb= (const float*)d_in[4];
    const float* Wkl = (const float*)d_in[5];   const float* bkl = (const float*)d_in[6];
    const float* Wvl = (const float*)d_in[7];   const float* bvl = (const float*)d_in[8];
    const float* Wkr = (const float*)d_in[9];   const float* bkr = (const float*)d_in[10];
    const float* Wvr = (const float*)d_in[11];  const float* bvr = (const float*)d_in[12];
    const float* Wkt = (const float*)d_in[13];  const float* bkt = (const float*)d_in[14];
    const float* Wvt = (const float*)d_in[15];  const float* bvt = (const float*)d_in[16];
    const float* ln1_g = (const float*)d_in[17]; const float* ln1_b = (const float*)d_in[18];
    const float* Wqkv  = (const float*)d_in[19]; const float* bqkv  = (const float*)d_in[20];
    const float* Wo    = (const float*)d_in[21]; const float* bo    = (const float*)d_in[22];
    const float* ln2_g = (const float*)d_in[23]; const float* ln2_b = (const float*)d_in[24];
    const float* W1 = (const float*)d_in[25];   const float* b1 = (const float*)d_in[26];
    const float* W2 = (const float*)d_in[27];   const float* b2 = (const float*)d_in[28];
    const float* lnf_g = (const float*)d_in[29]; const float* lnf_b = (const float*)d_in[30];
    const float* W_head = (const float*)d_in[31]; const float* b_head = (const float*)d_in[32];

    // Workspace layout (bytes): total ~72.5 MB
    char* p = (char*)d_ws;
    float* h0 = (float*)p;                    p += (size_t)MP * 256 * 4;
    float* h1 = (float*)p;                    p += (size_t)MP * 256 * 4;
    unsigned short* qkb = (unsigned short*)p; p += (size_t)MP * 768 * 2;
    unsigned short* xnb = (unsigned short*)p; p += (size_t)MP * 256 * 2;
    unsigned short* ob  = (unsigned short*)p; p += (size_t)MP * 256 * 2;
    unsigned short* ff  = (unsigned short*)p; p += (size_t)MP * 3072 * 2;
    unsigned short* wb  = (unsigned short*)p;
    unsigned short* wqkv_b = wb;             // 196608
    unsigned short* wo_b   = wb + 196608;    // 65536
    unsigned short* w1_b   = wb + 262144;    // 786432
    unsigned short* w2_b   = wb + 1048576;   // 786432

    // rag scratch lives inside qkb (unused until the layer loop)
    float* ragws = (float*)qkb;
    float* M    = ragws;              // 32*256
    float* Ul   = ragws + 8192;
    float* Ur   = ragws + 2 * 8192;
    float* Ut   = ragws + 3 * 8192;
    float* cl   = ragws + 4 * 8192;   // 32
    float* cr   = cl + 32;
    float* ct   = cl + 64;
    float* fbuf = cl + 96;            // 30*256

    // ---- patch embedding as MFMA GEMM ----
    convert_kernel<<<64, 256, 0, stream>>>(W_patch, wqkv_b);   // Wp bf16 (wb free pre-loop)
    patchify_kernel<<<NPAT, 256, 0, stream>>>(x, xnb);
    cls_pos_kernel<<<Bz, 256, 0, stream>>>(cls_tok, pos_emb, h0);
    mfma_gemm64<3><<<dim3(4, NPAT / 128), 256, 0, stream>>>(
        xnb, 256, wqkv_b, 256, b_patch, h0, 256, 256, pos_emb);

    // ---- rag mixer (parallelized, fp32) ----
    means_kernel<<<Bz, 256, 0, stream>>>(h0, M);
    uvec_kernel<<<Bz, 256, 0, stream>>>(M, Wkl, bkl, Wkr, bkr, Wkt, bkt,
                                        Ul, Ur, Ut, cl, cr, ct);
    rag_score_kernel<<<(Bz - 2) * 4, 256, 0, stream>>>(
        h0, M, Ul, Ur, Ut, cl, cr, ct, Wvl, bvl, Wvr, bvr, Wvt, bvt, fbuf);
    rag_outer_kernel<<<(Bz - 2) * S, 256, 0, stream>>>(fbuf, M, h1);
    copy_edges<<<(2 * S * E + 255) / 256, 256, 0, stream>>>(h0, h1);

    const int gy = MP / 128;   // 50 M-tiles
    for (int l = 0; l < Ln; l++) {
        convert_w_kernel<<<1792, 256, 0, stream>>>(
            Wqkv + (size_t)l * 768 * 256, Wo + (size_t)l * 256 * 256,
            W1 + (size_t)l * Fd * 256, W2 + (size_t)l * 256 * Fd, wb);
        ln_kernel<<<MS / 4, 256, 0, stream>>>(h1, xnb, ln1_g + l * E, ln1_b + l * E);
        mfma_gemm<4><<<dim3(6, gy), 256, 0, stream>>>(
            xnb, 256, wqkv_b, 256, bqkv + l * 768, qkb, 768, 256);
        attn_kernel<<<Bz * Hn, 256, 0, stream>>>(qkb, ob);
        mfma_gemm64<1><<<dim3(4, gy), 256, 0, stream>>>(
            ob, 256, wo_b, 256, bo + l * 256, h1, 256, 256, nullptr);
        ln_kernel<<<MS / 4, 256, 0, stream>>>(h1, xnb, ln2_g + l * E, ln2_b + l * E);
        mfma_gemm<2><<<dim3(24, gy), 256, 0, stream>>>(
            xnb, 256, w1_b, 256, b1 + l * Fd, ff, 3072, 256);
        mfma_gemm_sk<<<dim3(8, MP / 64), 256, 0, stream>>>(
            ff, 3072, w2_b, 3072, b2 + l * 256, h1, 256, 3072, 8);
    }
    head_kernel<<<Bz, 256, 0, stream>>>(h1, lnf_g, lnf_b, W_head, b_head, (float*)d_out);
}

// Round 7
// 1785.653 us; speedup vs baseline: 1.0605x; 1.0605x over previous
//
#include <hip/hip_runtime.h>
#include <hip/hip_bf16.h>
#include <math.h>

// Problem constants
constexpr int Bz  = 32;
constexpr int S   = 197;
constexpr int E   = 256;
constexpr int Hn  = 16;
constexpr int HD  = 16;
constexpr int Fd  = 3072;
constexpr int Ln  = 12;
constexpr int MS  = Bz * S;         // 6304 tokens
constexpr int MP  = 6400;           // padded to 50 * 128 for MFMA GEMM tiles
constexpr int NPAT = 6272;          // 32*196 patches = 49*128 exactly
constexpr int DVL = 50, DVR = 49, DVT = 49;

typedef __attribute__((ext_vector_type(8))) short short8;   // 8 bf16 = 4 VGPRs
typedef __attribute__((ext_vector_type(4))) short short4v;
typedef __attribute__((ext_vector_type(4))) float f32x4;

__device__ __forceinline__ unsigned short f2bf(float f) {
    unsigned int u = __float_as_uint(f);
    u = (u + 0x7FFFu + ((u >> 16) & 1u)) >> 16;             // RNE
    return (unsigned short)u;
}

// async global->LDS, 16 B per lane. LDS dest is wave-uniform base + lane*16.
__device__ __forceinline__ void gload_lds16(const void* g, void* l) {
    __builtin_amdgcn_global_load_lds(
        (const __attribute__((address_space(1))) void*)g,
        (__attribute__((address_space(3))) void*)l, 16, 0, 0);
}

// wave reduce (64 lanes), op 0=sum 1=max
__device__ __forceinline__ float wave_reduce(float v, int op) {
    #pragma unroll
    for (int off = 32; off > 0; off >>= 1) {
        float o = __shfl_xor(v, off, 64);
        v = op ? fmaxf(v, o) : v + o;
    }
    return v;
}

// block-wide reduce (256 thr): wave shuffle + 4-slot LDS. op: 0=sum, 1=max.
__device__ __forceinline__ float block_reduce(float v, float* red4, int op) {
    v = wave_reduce(v, op);
    int w = threadIdx.x >> 6;
    if ((threadIdx.x & 63) == 0) red4[w] = v;
    __syncthreads();
    float r = op ? fmaxf(fmaxf(red4[0], red4[1]), fmaxf(red4[2], red4[3]))
                 : (red4[0] + red4[1] + red4[2] + red4[3]);
    __syncthreads();
    return r;
}

// ---------------------------------------------------------------------------
// Patchify: x (B,1,224,224) -> bf16 A[6272][256], A[b*196+q][pr*16+pc].
__global__ __launch_bounds__(256) void patchify_kernel(
        const float* __restrict__ x, unsigned short* __restrict__ Ab) {
    int pi = blockIdx.x;                 // 0..6271
    int b = pi / 196, q = pi % 196;
    int i = q / 14, j = q % 14;
    int e = threadIdx.x, pr = e >> 4, pc = e & 15;
    float v = x[((size_t)(b * 224 + i * 16 + pr)) * 224 + j * 16 + pc];
    Ab[(size_t)pi * 256 + e] = f2bf(v);
}

// cls token rows of h0
__global__ __launch_bounds__(256) void cls_pos_kernel(
        const float* __restrict__ cls, const float* __restrict__ pos,
        float* __restrict__ h0) {
    int b = blockIdx.x, e = threadIdx.x;
    h0[(size_t)(b * S) * E + e] = cls[e] + pos[e];
}

// fp32 -> bf16, 4 elems/thread
__global__ __launch_bounds__(256) void convert_kernel(
        const float* __restrict__ src, unsigned short* __restrict__ dst) {
    int i4 = (blockIdx.x * 256 + threadIdx.x) * 4;
    float4 v = *(const float4*)(src + i4);
    ushort4 o;
    o.x = f2bf(v.x); o.y = f2bf(v.y); o.z = f2bf(v.z); o.w = f2bf(v.w);
    *(ushort4*)(dst + i4) = o;
}

// ---------------------------------------------------------------------------
// rag stage 1: per-sample token means. grid 32, 256 thr, coalesced.
__global__ __launch_bounds__(256) void means_kernel(
        const float* __restrict__ h0, float* __restrict__ M) {
    int b = blockIdx.x, e = threadIdx.x;
    float s = 0.f;
    for (int t = 0; t < S; t++) s += h0[((size_t)(b * S + t)) * E + e];
    M[b * E + e] = s * (1.f / (float)S);
}

// rag stage 2: U_x[t] = Wk_x.T @ M[t], c_x[t] = bk_x . M[t]. grid 32.
__global__ __launch_bounds__(256) void uvec_kernel(
        const float* __restrict__ M,
        const float* __restrict__ Wkl, const float* __restrict__ bkl,
        const float* __restrict__ Wkr, const float* __restrict__ bkr,
        const float* __restrict__ Wkt, const float* __restrict__ bkt,
        float* __restrict__ Ul, float* __restrict__ Ur, float* __restrict__ Ut,
        float* __restrict__ cl, float* __restrict__ cr, float* __restrict__ ct) {
    __shared__ float red4[4];
    int t = blockIdx.x, e = threadIdx.x;
    const float* mt = M + t * E;
    float a0 = 0.f, a1 = 0.f, a2 = 0.f;
    for (int i = 0; i < 256; i++) {
        float mi = mt[i];                       // wave-uniform -> s_load
        a0 += Wkl[(size_t)i * 256 + e] * mi;
        a1 += Wkr[(size_t)i * 256 + e] * mi;
        a2 += Wkt[(size_t)i * 256 + e] * mi;
    }
    Ul[t * E + e] = a0; Ur[t * E + e] = a1; Ut[t * E + e] = a2;
    float me = mt[e];
    float c0 = block_reduce(bkl[e] * me, red4, 0);
    float c1 = block_reduce(bkr[e] * me, red4, 0);
    float c2 = block_reduce(bkt[e] * me, red4, 0);
    if (e == 0) { cl[t] = c0; cr[t] = c1; ct[t] = c2; }
}

// rag stage 3: scores+softmax+xbar+f for one (t, branch). grid 120, 256 thr.
__global__ __launch_bounds__(256) void rag_score_kernel(
        const float* __restrict__ h0, const float* __restrict__ M,
        const float* __restrict__ Ul, const float* __restrict__ Ur,
        const float* __restrict__ Ut,
        const float* __restrict__ cl, const float* __restrict__ cr,
        const float* __restrict__ ct,
        const float* __restrict__ Wvl, const float* __restrict__ bvl,
        const float* __restrict__ Wvr, const float* __restrict__ bvr,
        const float* __restrict__ Wvt, const float* __restrict__ bvt,
        float* __restrict__ fbuf) {
    int t = blockIdx.x >> 2, br = blockIdx.x & 3;
    const float* xsrc; const float* u; float c;
    const float* Wv; const float* bv; int dv, fo;
    if (br == 0)      { xsrc = h0 + (size_t)t * S * E;       u = Ul + (t+1)*E; c = cl[t+1]; Wv = Wvl; bv = bvl; dv = DVL; fo = 0; }
    else if (br == 1) { xsrc = h0 + (size_t)(t+1) * S * E;   u = Ut + t*E;     c = ct[t];   Wv = Wvt; bv = bvt; dv = DVT; fo = DVL; }
    else if (br == 2) { xsrc = h0 + (size_t)(t+1) * S * E;   u = Ut + (t+2)*E; c = ct[t+2]; Wv = Wvt; bv = bvt; dv = DVT; fo = DVL + DVT; }
    else              { xsrc = h0 + (size_t)(t+2) * S * E;   u = Ur + (t+1)*E; c = cr[t+1]; Wv = Wvr; bv = bvr; dv = DVR; fo = DVL + 2*DVT; }
    __shared__ float us[256], sc[200], xbar[256], red4[4];
    int tid = threadIdx.x, w = tid >> 6, lane = tid & 63;
    us[tid] = u[tid];
    __syncthreads();
    float4 u4 = *(float4*)&us[lane * 4];
    for (int s = w; s < S; s += 4) {
        float4 x4 = *(const float4*)&xsrc[(size_t)s * E + lane * 4];
        float p = x4.x*u4.x + x4.y*u4.y + x4.z*u4.z + x4.w*u4.w;
        p = wave_reduce(p, 0);
        if (lane == 0) sc[s] = (p + c) * 0.0625f;     // 1/sqrt(E)
    }
    __syncthreads();
    float v = (tid < S) ? sc[tid] : -1e30f;
    float mx = block_reduce(v, red4, 1);
    float ex = (tid < S) ? expf(v - mx) : 0.f;
    float dn = block_reduce(ex, red4, 0);
    if (tid < S) sc[tid] = ex / dn;
    __syncthreads();
    float xb = 0.f;
    for (int s = 0; s < S; s++) xb += sc[s] * xsrc[(size_t)s * E + tid];
    xbar[tid] = xb;
    __syncthreads();
    float4 xb4 = *(float4*)&xbar[lane * 4];
    for (int d = w; d < dv; d += 4) {
        float4 w4 = *(const float4*)&Wv[(size_t)d * E + lane * 4];
        float p = w4.x*xb4.x + w4.y*xb4.y + w4.z*xb4.z + w4.w*xb4.w;
        p = wave_reduce(p, 0);
        if (lane == 0) fbuf[t * 256 + fo + d] = p + bv[d];
    }
}

// rag stage 4: outer product h1[t+1][s][:] = f[t][s] * M[t+1][:]
__global__ __launch_bounds__(256) void rag_outer_kernel(
        const float* __restrict__ fbuf, const float* __restrict__ M,
        float* __restrict__ h1) {
    int bid = blockIdx.x;                    // 0..30*197-1
    int t = bid / S, s = bid % S;
    float f = fbuf[t * 256 + s];             // uniform
    int e = threadIdx.x;
    h1[((size_t)((t + 1) * S + s)) * E + e] = f * M[(t + 1) * E + e];
}

// copy h0 samples 0 and 31 into h1
__global__ __launch_bounds__(256) void copy_edges(const float* __restrict__ h0,
                                                  float* __restrict__ h1) {
    int i = blockIdx.x * 256 + threadIdx.x;
    int n = S * E;
    if (i < n) h1[i] = h0[i];
    else if (i < 2 * n) {
        int j = i - n;
        size_t o = (size_t)31 * S * E + j;
        h1[o] = h0[o];
    }
}

// ---------------------------------------------------------------------------
// LayerNorm over E=256: wave per token, float4, shuffle-only. grid MS/4.
__global__ __launch_bounds__(256) void ln_kernel(const float* __restrict__ in,
                                                 unsigned short* __restrict__ out,
                                                 const float* __restrict__ g,
                                                 const float* __restrict__ b) {
    int w = threadIdx.x >> 6, lane = threadIdx.x & 63;
    int tok = blockIdx.x * 4 + w;
    const float* row = in + (size_t)tok * E;
    float4 v = *(const float4*)&row[lane * 4];
    float mean = wave_reduce(v.x + v.y + v.z + v.w, 0) * (1.f / 256.f);
    float dx = v.x - mean, dy = v.y - mean, dz = v.z - mean, dw = v.w - mean;
    float var = wave_reduce(dx*dx + dy*dy + dz*dz + dw*dw, 0) * (1.f / 256.f);
    float inv = rsqrtf(var + 1e-5f);
    float4 gg = *(const float4*)&g[lane * 4];
    float4 bb = *(const float4*)&b[lane * 4];
    ushort4 o;
    o.x = f2bf(dx * inv * gg.x + bb.x);
    o.y = f2bf(dy * inv * gg.y + bb.y);
    o.z = f2bf(dz * inv * gg.z + bb.z);
    o.w = f2bf(dw * inv * gg.w + bb.w);
    *(ushort4*)&out[(size_t)tok * E + lane * 4] = o;
}

// ---------------------------------------------------------------------------
// Per-layer weight conversion fp32 -> bf16 into staging buffer.
__global__ __launch_bounds__(256) void convert_w_kernel(
        const float* __restrict__ wqkv, const float* __restrict__ wo,
        const float* __restrict__ w1, const float* __restrict__ w2,
        unsigned short* __restrict__ out) {
    int idx = blockIdx.x * 256 + threadIdx.x;       // 0..458751
    int i4 = idx * 4;
    const float* src;
    if (i4 < 196608)       src = wqkv + i4;
    else if (i4 < 262144)  src = wo + (i4 - 196608);
    else if (i4 < 1048576) src = w1 + (i4 - 262144);
    else                   src = w2 + (i4 - 1048576);
    float4 v = *(const float4*)src;
    ushort4 o;
    o.x = f2bf(v.x); o.y = f2bf(v.y); o.z = f2bf(v.z); o.w = f2bf(v.w);
    *(ushort4*)(out + i4) = o;
}

// ---------------------------------------------------------------------------
// bf16 MFMA GEMM, 128x128 tile, BK=64, global_load_lds staging, XOR-swizzled
// LDS. DB=1: two-stage double buffer — one barrier/iter, loads for k+1
// issued right after the barrier so __syncthreads' vmcnt(0) drain IS the
// pipeline wait. DB=0: classic 2-barrier single buffer (for high-occupancy
// grids where doubling LDS would cut blocks/CU — m132 lesson).
// MODE 0: fp32 store (+bias) | MODE 2: gelu -> bf16 | MODE 4: bf16 store
template <int MODE, int DB>
__global__ __launch_bounds__(256) void mfma_gemm(
        const unsigned short* __restrict__ A, int lda,
        const unsigned short* __restrict__ W, int ldw,
        const float* __restrict__ bias,
        void* __restrict__ Cv, int ldc, int K) {
    __shared__ unsigned short As[(DB + 1) * 128 * 64];
    __shared__ unsigned short Bs[(DB + 1) * 128 * 64];
    const int m0 = blockIdx.y * 128, n0 = blockIdx.x * 128;
    const int tid = threadIdx.x, wave = tid >> 6, lane = tid & 63;
    const int wm = (wave >> 1) * 64, wn = (wave & 1) * 64;
    const int lr = lane & 15, kg = lane >> 4;
    const int srow = wave * 32 + (lane >> 3);           // +q*8
    const int scol = ((lane & 7) ^ (lane >> 3)) * 8;    // swizzled granule col
    auto stage = [&](int bb, int k0) {
        #pragma unroll
        for (int q = 0; q < 4; q++) {
            gload_lds16(&A[(size_t)(m0 + srow + q * 8) * lda + k0 + scol],
                        &As[bb * 8192 + (wave * 4 + q) * 512]);
            gload_lds16(&W[(size_t)(n0 + srow + q * 8) * ldw + k0 + scol],
                        &Bs[bb * 8192 + (wave * 4 + q) * 512]);
        }
    };
    const int nIter = K >> 6;
    if (DB) stage(0, 0);
    f32x4 acc[4][4] = {};
    for (int i = 0; i < nIter; i++) {
        if (!DB) {
            if (i > 0) __syncthreads();
            stage(0, i * 64);
        }
        __syncthreads();
        if (DB && i + 1 < nIter) stage((i + 1) & 1, (i + 1) * 64);
        const int bb = DB ? (i & 1) : 0;
        #pragma unroll
        for (int h = 0; h < 2; h++) {
            const int sw = ((h * 4 + kg) ^ (lr & 7)) * 8;
            short8 af[4], bfr[4];
            #pragma unroll
            for (int i2 = 0; i2 < 4; i2++) af[i2]  = *(short8*)&As[bb * 8192 + (wm + i2 * 16 + lr) * 64 + sw];
            #pragma unroll
            for (int j = 0; j < 4; j++) bfr[j] = *(short8*)&Bs[bb * 8192 + (wn + j * 16 + lr) * 64 + sw];
            #pragma unroll
            for (int i2 = 0; i2 < 4; i2++)
                #pragma unroll
                for (int j = 0; j < 4; j++)
                    acc[i2][j] = __builtin_amdgcn_mfma_f32_16x16x32_bf16(af[i2], bfr[j], acc[i2][j], 0, 0, 0);
        }
    }
    #pragma unroll
    for (int j = 0; j < 4; j++) {
        int n = n0 + wn + j * 16 + lr;
        float bv = bias ? bias[n] : 0.f;
        #pragma unroll
        for (int i = 0; i < 4; i++) {
            #pragma unroll
            for (int r = 0; r < 4; r++) {
                size_t m = (size_t)(m0 + wm + i * 16 + kg * 4 + r);
                float v = acc[i][j][r] + bv;
                if (MODE == 0) ((float*)Cv)[m * ldc + n] = v;
                if (MODE == 2) {
                    v = 0.5f * v * (1.f + erff(v * 0.70710678118654752f));
                    ((unsigned short*)Cv)[m * ldc + n] = f2bf(v);
                }
                if (MODE == 4) ((unsigned short*)Cv)[m * ldc + n] = f2bf(v);
            }
        }
    }
}

// ---------------------------------------------------------------------------
// bf16 MFMA GEMM, 128x64 tile, BK=64, double-buffered (48 KB LDS -> 3
// blocks/CU). 4 waves x (32x64).
// MODE 1: fp32 += (+bias) | MODE 3: patch-embed epilogue (token remap + pos)
template <int MODE>
__global__ __launch_bounds__(256) void mfma_gemm64(
        const unsigned short* __restrict__ A, int lda,
        const unsigned short* __restrict__ W, int ldw,
        const float* __restrict__ bias,
        void* __restrict__ Cv, int ldc, int K,
        const float* __restrict__ pos) {
    __shared__ unsigned short As[2 * 128 * 64];
    __shared__ unsigned short Bs[2 * 64 * 64];
    const int m0 = blockIdx.y * 128, n0 = blockIdx.x * 64;
    const int tid = threadIdx.x, wave = tid >> 6, lane = tid & 63;
    const int wm = wave * 32;
    const int lr = lane & 15, kg = lane >> 4;
    const int srow = wave * 32 + (lane >> 3);
    const int brow = wave * 16 + (lane >> 3);
    const int scol = ((lane & 7) ^ (lane >> 3)) * 8;
    auto stage = [&](int bb, int k0) {
        #pragma unroll
        for (int q = 0; q < 4; q++)
            gload_lds16(&A[(size_t)(m0 + srow + q * 8) * lda + k0 + scol],
                        &As[bb * 8192 + (wave * 4 + q) * 512]);
        #pragma unroll
        for (int q = 0; q < 2; q++)
            gload_lds16(&W[(size_t)(n0 + brow + q * 8) * ldw + k0 + scol],
                        &Bs[bb * 4096 + (wave * 2 + q) * 512]);
    };
    const int nIter = K >> 6;
    stage(0, 0);
    f32x4 acc[2][4] = {};
    for (int i = 0; i < nIter; i++) {
        __syncthreads();
        if (i + 1 < nIter) stage((i + 1) & 1, (i + 1) * 64);
        const int bb = i & 1;
        #pragma unroll
        for (int h = 0; h < 2; h++) {
            const int sw = ((h * 4 + kg) ^ (lr & 7)) * 8;
            short8 af[2], bfr[4];
            #pragma unroll
            for (int i2 = 0; i2 < 2; i2++) af[i2]  = *(short8*)&As[bb * 8192 + (wm + i2 * 16 + lr) * 64 + sw];
            #pragma unroll
            for (int j = 0; j < 4; j++) bfr[j] = *(short8*)&Bs[bb * 4096 + (j * 16 + lr) * 64 + sw];
            #pragma unroll
            for (int i2 = 0; i2 < 2; i2++)
                #pragma unroll
                for (int j = 0; j < 4; j++)
                    acc[i2][j] = __builtin_amdgcn_mfma_f32_16x16x32_bf16(af[i2], bfr[j], acc[i2][j], 0, 0, 0);
        }
    }
    #pragma unroll
    for (int j = 0; j < 4; j++) {
        int n = n0 + j * 16 + lr;
        float bv = bias ? bias[n] : 0.f;
        #pragma unroll
        for (int i = 0; i < 2; i++) {
            #pragma unroll
            for (int r = 0; r < 4; r++) {
                int m = m0 + wm + i * 16 + kg * 4 + r;
                float v = acc[i][j][r] + bv;
                if (MODE == 1) ((float*)Cv)[(size_t)m * ldc + n] += v;
                if (MODE == 3) {
                    int b = m / 196, s = m - b * 196 + 1;   // token remap
                    ((float*)Cv)[((size_t)(b * S + s)) * E + n] = v + pos[(size_t)s * E + n];
                }
            }
        }
    }
}

// ---------------------------------------------------------------------------
// MFMA flash attention. One block per (b,h); 4 waves, each takes Q-tiles
// round-robin. qkv bf16 [MS][768]; out bf16 [MS][256].
__global__ __launch_bounds__(256) void attn_kernel(
        const unsigned short* __restrict__ qkv, unsigned short* __restrict__ o) {
    int b = blockIdx.x >> 4, hh = blockIdx.x & 15;
    __shared__ unsigned short Qs[208][32];
    __shared__ unsigned short Ks[208][32];
    __shared__ unsigned short Vt[16][224];
    __shared__ unsigned short Ps[4][16][224];
    int tid = threadIdx.x, wave = tid >> 6, lane = tid & 63;
    int lr = lane & 15, kg = lane >> 4;
    short8 z8 = {};
    if (tid < 208) {
        if (tid < 197) {
            size_t row = (size_t)(b * S + tid) * 768 + hh * 16;
            *(short8*)&Qs[tid][0] = *(const short8*)&qkv[row];
            *(short8*)&Qs[tid][8] = *(const short8*)&qkv[row + 8];
            *(short8*)&Ks[tid][0] = *(const short8*)&qkv[row + 256];
            *(short8*)&Ks[tid][8] = *(const short8*)&qkv[row + 264];
            union { short8 v8[2]; unsigned short u[16]; } vv;
            vv.v8[0] = *(const short8*)&qkv[row + 512];
            vv.v8[1] = *(const short8*)&qkv[row + 520];
            #pragma unroll
            for (int d = 0; d < 16; d++) Vt[d][tid] = vv.u[d];
        } else {
            *(short8*)&Qs[tid][0] = z8; *(short8*)&Qs[tid][8] = z8;
            *(short8*)&Ks[tid][0] = z8; *(short8*)&Ks[tid][8] = z8;
            #pragma unroll
            for (int d = 0; d < 16; d++) Vt[d][tid] = 0;
        }
        *(short8*)&Qs[tid][16] = z8; *(short8*)&Qs[tid][24] = z8;
        *(short8*)&Ks[tid][16] = z8; *(short8*)&Ks[tid][24] = z8;
    } else if (tid < 224) {
        #pragma unroll
        for (int d = 0; d < 16; d++) Vt[d][tid] = 0;
    }
    {   // zero P pad cols [208,224) of this wave's scratch
        short4v z4 = {};
        *(short4v*)&Ps[wave][lane >> 2][208 + (lane & 3) * 4] = z4;
    }
    __syncthreads();
    const f32x4 zf = {0.f, 0.f, 0.f, 0.f};
    for (int it = wave; it < 13; it += 4) {
        short8 qa = *(short8*)&Qs[it * 16 + lr][kg * 8];
        f32x4 sc[13];
        #pragma unroll
        for (int j = 0; j < 13; j++) {
            short8 kb = *(short8*)&Ks[j * 16 + lr][kg * 8];
            sc[j] = __builtin_amdgcn_mfma_f32_16x16x32_bf16(qa, kb, zf, 0, 0, 0);
        }
        float m[4] = {-1e30f, -1e30f, -1e30f, -1e30f};
        #pragma unroll
        for (int j = 0; j < 13; j++) {
            if (j * 16 + lr < 197) {
                #pragma unroll
                for (int r = 0; r < 4; r++) m[r] = fmaxf(m[r], sc[j][r]);
            }
        }
        #pragma unroll
        for (int off = 1; off < 16; off <<= 1)
            #pragma unroll
            for (int r = 0; r < 4; r++) m[r] = fmaxf(m[r], __shfl_xor(m[r], off, 64));
        float l[4] = {0.f, 0.f, 0.f, 0.f};
        #pragma unroll
        for (int j = 0; j < 13; j++) {
            bool valid = (j * 16 + lr) < 197;
            #pragma unroll
            for (int r = 0; r < 4; r++) {
                float p = valid ? __expf((sc[j][r] - m[r]) * 0.25f) : 0.f;
                l[r] += p;
                Ps[wave][kg * 4 + r][j * 16 + lr] = f2bf(p);
            }
        }
        #pragma unroll
        for (int off = 1; off < 16; off <<= 1)
            #pragma unroll
            for (int r = 0; r < 4; r++) l[r] += __shfl_xor(l[r], off, 64);
        f32x4 oa = zf;
        #pragma unroll
        for (int k0 = 0; k0 < 224; k0 += 32) {
            short8 pa = *(short8*)&Ps[wave][lr][k0 + kg * 8];
            short8 vb = *(short8*)&Vt[lr][k0 + kg * 8];
            oa = __builtin_amdgcn_mfma_f32_16x16x32_bf16(pa, vb, oa, 0, 0, 0);
        }
        #pragma unroll
        for (int r = 0; r < 4; r++) {
            int q = it * 16 + kg * 4 + r;
            if (q < 197)
                o[((size_t)(b * S + q)) * 256 + hh * 16 + lr] = f2bf(oa[r] / l[r]);
        }
    }
}

// ---------------------------------------------------------------------------
// Final LN on cls token + head GEMM. One block per sample.
__global__ __launch_bounds__(256) void head_kernel(
        const float* __restrict__ h, const float* __restrict__ g,
        const float* __restrict__ bb, const float* __restrict__ Wh,
        const float* __restrict__ bh, float* __restrict__ out) {
    __shared__ float red4[4];
    __shared__ float xs[256];
    int b = blockIdx.x, e = threadIdx.x;
    float v = h[((size_t)(b * S)) * E + e];
    float mean = block_reduce(v, red4, 0) * (1.f / 256.f);
    float d = v - mean;
    float var = block_reduce(d * d, red4, 0) * (1.f / 256.f);
    float xn = d * rsqrtf(var + 1e-5f) * g[e] + bb[e];
    xs[e] = xn;
    __syncthreads();
    for (int n = 0; n < 8; n++) {
        float s = block_reduce(xs[e] * Wh[(size_t)n * 256 + e], red4, 0);
        if (e == 0) out[b * 8 + n] = s + bh[n];
    }
}

// ---------------------------------------------------------------------------
extern "C" void kernel_launch(void* const* d_in, const int* in_sizes, int n_in,
                              void* d_out, int out_size, void* d_ws, size_t ws_size,
                              hipStream_t stream) {
    const float* x      = (const float*)d_in[0];
    const float* W_patch= (const float*)d_in[1];
    const float* b_patch= (const float*)d_in[2];
    const float* cls_tok= (const float*)d_in[3];
    const float* pos_emb= (const float*)d_in[4];
    const float* Wkl = (const float*)d_in[5];   const float* bkl = (const float*)d_in[6];
    const float* Wvl = (const float*)d_in[7];   const float* bvl = (const float*)d_in[8];
    const float* Wkr = (const float*)d_in[9];   const float* bkr = (const float*)d_in[10];
    const float* Wvr = (const float*)d_in[11];  const float* bvr = (const float*)d_in[12];
    const float* Wkt = (const float*)d_in[13];  const float* bkt = (const float*)d_in[14];
    const float* Wvt = (const float*)d_in[15];  const float* bvt = (const float*)d_in[16];
    const float* ln1_g = (const float*)d_in[17]; const float* ln1_b = (const float*)d_in[18];
    const float* Wqkv  = (const float*)d_in[19]; const float* bqkv  = (const float*)d_in[20];
    const float* Wo    = (const float*)d_in[21]; const float* bo    = (const float*)d_in[22];
    const float* ln2_g = (const float*)d_in[23]; const float* ln2_b = (const float*)d_in[24];
    const float* W1 = (const float*)d_in[25];   const float* b1 = (const float*)d_in[26];
    const float* W2 = (const float*)d_in[27];   const float* b2 = (const float*)d_in[28];
    const float* lnf_g = (const float*)d_in[29]; const float* lnf_b = (const float*)d_in[30];
    const float* W_head = (const float*)d_in[31]; const float* b_head = (const float*)d_in[32];

    // Workspace layout (bytes): total ~72.5 MB
    char* p = (char*)d_ws;
    float* h0 = (float*)p;                    p += (size_t)MP * 256 * 4;
    float* h1 = (float*)p;                    p += (size_t)MP * 256 * 4;
    unsigned short* qkb = (unsigned short*)p; p += (size_t)MP * 768 * 2;
    unsigned short* xnb = (unsigned short*)p; p += (size_t)MP * 256 * 2;
    unsigned short* ob  = (unsigned short*)p; p += (size_t)MP * 256 * 2;
    unsigned short* ff  = (unsigned short*)p; p += (size_t)MP * 3072 * 2;
    unsigned short* wb  = (unsigned short*)p;
    unsigned short* wqkv_b = wb;             // 196608
    unsigned short* wo_b   = wb + 196608;    // 65536
    unsigned short* w1_b   = wb + 262144;    // 786432
    unsigned short* w2_b   = wb + 1048576;   // 786432

    // rag scratch lives inside qkb (unused until the layer loop)
    float* ragws = (float*)qkb;
    float* M    = ragws;              // 32*256
    float* Ul   = ragws + 8192;
    float* Ur   = ragws + 2 * 8192;
    float* Ut   = ragws + 3 * 8192;
    float* cl   = ragws + 4 * 8192;   // 32
    float* cr   = cl + 32;
    float* ct   = cl + 64;
    float* fbuf = cl + 96;            // 30*256

    // ---- patch embedding as MFMA GEMM ----
    convert_kernel<<<64, 256, 0, stream>>>(W_patch, wqkv_b);   // Wp bf16 (wb free pre-loop)
    patchify_kernel<<<NPAT, 256, 0, stream>>>(x, xnb);
    cls_pos_kernel<<<Bz, 256, 0, stream>>>(cls_tok, pos_emb, h0);
    mfma_gemm64<3><<<dim3(4, NPAT / 128), 256, 0, stream>>>(
        xnb, 256, wqkv_b, 256, b_patch, h0, 256, 256, pos_emb);

    // ---- rag mixer (parallelized, fp32) ----
    means_kernel<<<Bz, 256, 0, stream>>>(h0, M);
    uvec_kernel<<<Bz, 256, 0, stream>>>(M, Wkl, bkl, Wkr, bkr, Wkt, bkt,
                                        Ul, Ur, Ut, cl, cr, ct);
    rag_score_kernel<<<(Bz - 2) * 4, 256, 0, stream>>>(
        h0, M, Ul, Ur, Ut, cl, cr, ct, Wvl, bvl, Wvr, bvr, Wvt, bvt, fbuf);
    rag_outer_kernel<<<(Bz - 2) * S, 256, 0, stream>>>(fbuf, M, h1);
    copy_edges<<<(2 * S * E + 255) / 256, 256, 0, stream>>>(h0, h1);

    const int gy = MP / 128;   // 50 M-tiles
    for (int l = 0; l < Ln; l++) {
        convert_w_kernel<<<1792, 256, 0, stream>>>(
            Wqkv + (size_t)l * 768 * 256, Wo + (size_t)l * 256 * 256,
            W1 + (size_t)l * Fd * 256, W2 + (size_t)l * 256 * Fd, wb);
        ln_kernel<<<MS / 4, 256, 0, stream>>>(h1, xnb, ln1_g + l * E, ln1_b + l * E);
        mfma_gemm<4, 1><<<dim3(6, gy), 256, 0, stream>>>(
            xnb, 256, wqkv_b, 256, bqkv + l * 768, qkb, 768, 256);
        attn_kernel<<<Bz * Hn, 256, 0, stream>>>(qkb, ob);
        mfma_gemm64<1><<<dim3(4, gy), 256, 0, stream>>>(
            ob, 256, wo_b, 256, bo + l * 256, h1, 256, 256, nullptr);
        ln_kernel<<<MS / 4, 256, 0, stream>>>(h1, xnb, ln2_g + l * E, ln2_b + l * E);
        mfma_gemm<2, 0><<<dim3(24, gy), 256, 0, stream>>>(
            xnb, 256, w1_b, 256, b1 + l * Fd, ff, 3072, 256);
        mfma_gemm64<1><<<dim3(4, gy), 256, 0, stream>>>(
            ff, 3072, w2_b, 3072, b2 + l * 256, h1, 256, 3072, nullptr);
    }
    head_kernel<<<Bz, 256, 0, stream>>>(h1, lnf_g, lnf_b, W_head, b_head, (float*)d_out);
}

// Round 8
// 1748.326 us; speedup vs baseline: 1.0831x; 1.0214x over previous
//
#include <hip/hip_runtime.h>
#include <hip/hip_bf16.h>
#include <math.h>

// Problem constants
constexpr int Bz  = 32;
constexpr int S   = 197;
constexpr int E   = 256;
constexpr int Hn  = 16;
constexpr int HD  = 16;
constexpr int Fd  = 3072;
constexpr int Ln  = 12;
constexpr int MS  = Bz * S;         // 6304 tokens
constexpr int MP  = 6400;           // padded: 100 m-tiles of 64
constexpr int NPAT = 6272;          // 32*196 patches = 98 * 64
constexpr int DVL = 50, DVR = 49, DVT = 49;
constexpr size_t WLSTRIDE = 1835008;  // bf16 weights per layer

typedef __attribute__((ext_vector_type(8))) short short8;   // 8 bf16 = 4 VGPRs
typedef __attribute__((ext_vector_type(4))) short short4v;
typedef __attribute__((ext_vector_type(4))) float f32x4;

__device__ __forceinline__ unsigned short f2bf(float f) {
    unsigned int u = __float_as_uint(f);
    u = (u + 0x7FFFu + ((u >> 16) & 1u)) >> 16;             // RNE
    return (unsigned short)u;
}

// async global->LDS, 16 B per lane. LDS dest is wave-uniform base + lane*16.
__device__ __forceinline__ void gload_lds16(const void* g, void* l) {
    __builtin_amdgcn_global_load_lds(
        (const __attribute__((address_space(1))) void*)g,
        (__attribute__((address_space(3))) void*)l, 16, 0, 0);
}

// wave reduce (64 lanes), op 0=sum 1=max
__device__ __forceinline__ float wave_reduce(float v, int op) {
    #pragma unroll
    for (int off = 32; off > 0; off >>= 1) {
        float o = __shfl_xor(v, off, 64);
        v = op ? fmaxf(v, o) : v + o;
    }
    return v;
}

// block-wide reduce (256 thr): wave shuffle + 4-slot LDS. op: 0=sum, 1=max.
__device__ __forceinline__ float block_reduce(float v, float* red4, int op) {
    v = wave_reduce(v, op);
    int w = threadIdx.x >> 6;
    if ((threadIdx.x & 63) == 0) red4[w] = v;
    __syncthreads();
    float r = op ? fmaxf(fmaxf(red4[0], red4[1]), fmaxf(red4[2], red4[3]))
                 : (red4[0] + red4[1] + red4[2] + red4[3]);
    __syncthreads();
    return r;
}

// ---------------------------------------------------------------------------
// Patchify: x (B,1,224,224) -> bf16 A[6272][256], A[b*196+q][pr*16+pc].
__global__ __launch_bounds__(256) void patchify_kernel(
        const float* __restrict__ x, unsigned short* __restrict__ Ab) {
    int pi = blockIdx.x;                 // 0..6271
    int b = pi / 196, q = pi % 196;
    int i = q / 14, j = q % 14;
    int e = threadIdx.x, pr = e >> 4, pc = e & 15;
    float v = x[((size_t)(b * 224 + i * 16 + pr)) * 224 + j * 16 + pc];
    Ab[(size_t)pi * 256 + e] = f2bf(v);
}

// cls token rows of h0
__global__ __launch_bounds__(256) void cls_pos_kernel(
        const float* __restrict__ cls, const float* __restrict__ pos,
        float* __restrict__ h0) {
    int b = blockIdx.x, e = threadIdx.x;
    h0[(size_t)(b * S) * E + e] = cls[e] + pos[e];
}

// fp32 -> bf16, 4 elems/thread
__global__ __launch_bounds__(256) void convert_kernel(
        const float* __restrict__ src, unsigned short* __restrict__ dst) {
    int i4 = (blockIdx.x * 256 + threadIdx.x) * 4;
    float4 v = *(const float4*)(src + i4);
    ushort4 o;
    o.x = f2bf(v.x); o.y = f2bf(v.y); o.z = f2bf(v.z); o.w = f2bf(v.w);
    *(ushort4*)(dst + i4) = o;
}

// ALL layers' weights fp32 -> bf16 in one dispatch. grid 21504 x 256.
// Per-layer segments: [0,196608) Wqkv | ..262144 Wo | ..1048576 W1 | ..1835008 W2
__global__ __launch_bounds__(256) void convert_w_all_kernel(
        const float* __restrict__ wqkv, const float* __restrict__ wo,
        const float* __restrict__ w1, const float* __restrict__ w2,
        unsigned short* __restrict__ out) {
    size_t idx = (size_t)blockIdx.x * 256 + threadIdx.x;   // 0..5505023
    int l = (int)(idx / 458752);
    int r4 = (int)(idx % 458752) * 4;
    const float* src;
    if (r4 < 196608)       src = wqkv + (size_t)l * 196608 + r4;
    else if (r4 < 262144)  src = wo   + (size_t)l * 65536  + (r4 - 196608);
    else if (r4 < 1048576) src = w1   + (size_t)l * 786432 + (r4 - 262144);
    else                   src = w2   + (size_t)l * 786432 + (r4 - 1048576);
    float4 v = *(const float4*)src;
    ushort4 o;
    o.x = f2bf(v.x); o.y = f2bf(v.y); o.z = f2bf(v.z); o.w = f2bf(v.w);
    *(ushort4*)(out + (size_t)l * WLSTRIDE + r4) = o;
}

// ---------------------------------------------------------------------------
// rag stage 1: per-sample token means. grid 32, 256 thr, coalesced.
__global__ __launch_bounds__(256) void means_kernel(
        const float* __restrict__ h0, float* __restrict__ M) {
    int b = blockIdx.x, e = threadIdx.x;
    float s = 0.f;
    for (int t = 0; t < S; t++) s += h0[((size_t)(b * S + t)) * E + e];
    M[b * E + e] = s * (1.f / (float)S);
}

// rag stage 2: U_x[t] = Wk_x.T @ M[t], c_x[t] = bk_x . M[t]. grid 32.
__global__ __launch_bounds__(256) void uvec_kernel(
        const float* __restrict__ M,
        const float* __restrict__ Wkl, const float* __restrict__ bkl,
        const float* __restrict__ Wkr, const float* __restrict__ bkr,
        const float* __restrict__ Wkt, const float* __restrict__ bkt,
        float* __restrict__ Ul, float* __restrict__ Ur, float* __restrict__ Ut,
        float* __restrict__ cl, float* __restrict__ cr, float* __restrict__ ct) {
    __shared__ float red4[4];
    int t = blockIdx.x, e = threadIdx.x;
    const float* mt = M + t * E;
    float a0 = 0.f, a1 = 0.f, a2 = 0.f;
    for (int i = 0; i < 256; i++) {
        float mi = mt[i];                       // wave-uniform -> s_load
        a0 += Wkl[(size_t)i * 256 + e] * mi;
        a1 += Wkr[(size_t)i * 256 + e] * mi;
        a2 += Wkt[(size_t)i * 256 + e] * mi;
    }
    Ul[t * E + e] = a0; Ur[t * E + e] = a1; Ut[t * E + e] = a2;
    float me = mt[e];
    float c0 = block_reduce(bkl[e] * me, red4, 0);
    float c1 = block_reduce(bkr[e] * me, red4, 0);
    float c2 = block_reduce(bkt[e] * me, red4, 0);
    if (e == 0) { cl[t] = c0; cr[t] = c1; ct[t] = c2; }
}

// rag stage 3: scores+softmax+xbar+f for one (t, branch). grid 120, 256 thr.
__global__ __launch_bounds__(256) void rag_score_kernel(
        const float* __restrict__ h0, const float* __restrict__ M,
        const float* __restrict__ Ul, const float* __restrict__ Ur,
        const float* __restrict__ Ut,
        const float* __restrict__ cl, const float* __restrict__ cr,
        const float* __restrict__ ct,
        const float* __restrict__ Wvl, const float* __restrict__ bvl,
        const float* __restrict__ Wvr, const float* __restrict__ bvr,
        const float* __restrict__ Wvt, const float* __restrict__ bvt,
        float* __restrict__ fbuf) {
    int t = blockIdx.x >> 2, br = blockIdx.x & 3;
    const float* xsrc; const float* u; float c;
    const float* Wv; const float* bv; int dv, fo;
    if (br == 0)      { xsrc = h0 + (size_t)t * S * E;       u = Ul + (t+1)*E; c = cl[t+1]; Wv = Wvl; bv = bvl; dv = DVL; fo = 0; }
    else if (br == 1) { xsrc = h0 + (size_t)(t+1) * S * E;   u = Ut + t*E;     c = ct[t];   Wv = Wvt; bv = bvt; dv = DVT; fo = DVL; }
    else if (br == 2) { xsrc = h0 + (size_t)(t+1) * S * E;   u = Ut + (t+2)*E; c = ct[t+2]; Wv = Wvt; bv = bvt; dv = DVT; fo = DVL + DVT; }
    else              { xsrc = h0 + (size_t)(t+2) * S * E;   u = Ur + (t+1)*E; c = cr[t+1]; Wv = Wvr; bv = bvr; dv = DVR; fo = DVL + 2*DVT; }
    __shared__ float us[256], sc[200], xbar[256], red4[4];
    int tid = threadIdx.x, w = tid >> 6, lane = tid & 63;
    us[tid] = u[tid];
    __syncthreads();
    float4 u4 = *(float4*)&us[lane * 4];
    for (int s = w; s < S; s += 4) {
        float4 x4 = *(const float4*)&xsrc[(size_t)s * E + lane * 4];
        float p = x4.x*u4.x + x4.y*u4.y + x4.z*u4.z + x4.w*u4.w;
        p = wave_reduce(p, 0);
        if (lane == 0) sc[s] = (p + c) * 0.0625f;     // 1/sqrt(E)
    }
    __syncthreads();
    float v = (tid < S) ? sc[tid] : -1e30f;
    float mx = block_reduce(v, red4, 1);
    float ex = (tid < S) ? expf(v - mx) : 0.f;
    float dn = block_reduce(ex, red4, 0);
    if (tid < S) sc[tid] = ex / dn;
    __syncthreads();
    float xb = 0.f;
    for (int s = 0; s < S; s++) xb += sc[s] * xsrc[(size_t)s * E + tid];
    xbar[tid] = xb;
    __syncthreads();
    float4 xb4 = *(float4*)&xbar[lane * 4];
    for (int d = w; d < dv; d += 4) {
        float4 w4 = *(const float4*)&Wv[(size_t)d * E + lane * 4];
        float p = w4.x*xb4.x + w4.y*xb4.y + w4.z*xb4.z + w4.w*xb4.w;
        p = wave_reduce(p, 0);
        if (lane == 0) fbuf[t * 256 + fo + d] = p + bv[d];
    }
}

// rag stage 4: outer product h1[t+1][s][:] = f[t][s] * M[t+1][:]
__global__ __launch_bounds__(256) void rag_outer_kernel(
        const float* __restrict__ fbuf, const float* __restrict__ M,
        float* __restrict__ h1) {
    int bid = blockIdx.x;                    // 0..30*197-1
    int t = bid / S, s = bid % S;
    float f = fbuf[t * 256 + s];             // uniform
    int e = threadIdx.x;
    h1[((size_t)((t + 1) * S + s)) * E + e] = f * M[(t + 1) * E + e];
}

// copy h0 samples 0 and 31 into h1
__global__ __launch_bounds__(256) void copy_edges(const float* __restrict__ h0,
                                                  float* __restrict__ h1) {
    int i = blockIdx.x * 256 + threadIdx.x;
    int n = S * E;
    if (i < n) h1[i] = h0[i];
    else if (i < 2 * n) {
        int j = i - n;
        size_t o = (size_t)31 * S * E + j;
        h1[o] = h0[o];
    }
}

// ---------------------------------------------------------------------------
// LayerNorm over E=256: wave per token, float4, shuffle-only. grid MS/4.
__global__ __launch_bounds__(256) void ln_kernel(const float* __restrict__ in,
                                                 unsigned short* __restrict__ out,
                                                 const float* __restrict__ g,
                                                 const float* __restrict__ b) {
    int w = threadIdx.x >> 6, lane = threadIdx.x & 63;
    int tok = blockIdx.x * 4 + w;
    const float* row = in + (size_t)tok * E;
    float4 v = *(const float4*)&row[lane * 4];
    float mean = wave_reduce(v.x + v.y + v.z + v.w, 0) * (1.f / 256.f);
    float dx = v.x - mean, dy = v.y - mean, dz = v.z - mean, dw = v.w - mean;
    float var = wave_reduce(dx*dx + dy*dy + dz*dz + dw*dw, 0) * (1.f / 256.f);
    float inv = rsqrtf(var + 1e-5f);
    float4 gg = *(const float4*)&g[lane * 4];
    float4 bb = *(const float4*)&b[lane * 4];
    ushort4 o;
    o.x = f2bf(dx * inv * gg.x + bb.x);
    o.y = f2bf(dy * inv * gg.y + bb.y);
    o.z = f2bf(dz * inv * gg.z + bb.z);
    o.w = f2bf(dw * inv * gg.w + bb.w);
    *(ushort4*)&out[(size_t)tok * E + lane * 4] = o;
}

// ---------------------------------------------------------------------------
// Universal 64x64-tile bf16 MFMA GEMM. BK=64, double-buffered (32 KB LDS),
// global_load_lds staging, XOR-swizzled LDS, flat XCD-swizzled grid:
//   mt = (id&7) + 8*(id/(8*NT)), nt = (id>>3)%NT
// -> all NT n-tiles of one m-tile land on the same XCD (id%8 invariant):
//    A-tile fetched from HBM once, L2-served for the rest.
// Launch ceil(MT/8)*8*NT blocks; blocks with mt>=MT exit.
// MODE 1: fp32 += (+bias) | MODE 2: gelu->bf16 | MODE 3: patch epilogue
// MODE 4: bf16 store (+bias)
template <int MODE>
__global__ __launch_bounds__(256) void gemm_s64(
        const unsigned short* __restrict__ A, int lda,
        const unsigned short* __restrict__ W, int ldw,
        const float* __restrict__ bias,
        void* __restrict__ Cv, int ldc, int K, int MT, int NT,
        const float* __restrict__ pos) {
    __shared__ unsigned short As[2 * 64 * 64];
    __shared__ unsigned short Bs[2 * 64 * 64];
    const int id = blockIdx.x;
    const int mt = (id & 7) + 8 * (id / (8 * NT));
    const int nt = (id >> 3) % NT;
    if (mt >= MT) return;
    const int m0 = mt * 64, n0 = nt * 64;
    const int tid = threadIdx.x, wave = tid >> 6, lane = tid & 63;
    const int lr = lane & 15, kg = lane >> 4;
    const int srow = wave * 16 + (lane >> 3);           // +q*8
    const int scol = ((lane & 7) ^ (lane >> 3)) * 8;    // swizzled granule col
    auto stage = [&](int bb, int k0) {
        #pragma unroll
        for (int q = 0; q < 2; q++) {
            gload_lds16(&A[(size_t)(m0 + srow + q * 8) * lda + k0 + scol],
                        &As[bb * 4096 + (wave * 16 + q * 8) * 64]);
            gload_lds16(&W[(size_t)(n0 + srow + q * 8) * ldw + k0 + scol],
                        &Bs[bb * 4096 + (wave * 16 + q * 8) * 64]);
        }
    };
    const int nIter = K >> 6;
    stage(0, 0);
    f32x4 acc[4] = {};
    for (int i = 0; i < nIter; i++) {
        __syncthreads();
        if (i + 1 < nIter) stage((i + 1) & 1, (i + 1) * 64);
        const int bb = i & 1;
        #pragma unroll
        for (int h = 0; h < 2; h++) {
            const int sw = ((h * 4 + kg) ^ (lr & 7)) * 8;
            short8 af = *(short8*)&As[bb * 4096 + (wave * 16 + lr) * 64 + sw];
            #pragma unroll
            for (int j = 0; j < 4; j++) {
                short8 bf = *(short8*)&Bs[bb * 4096 + (j * 16 + lr) * 64 + sw];
                acc[j] = __builtin_amdgcn_mfma_f32_16x16x32_bf16(af, bf, acc[j], 0, 0, 0);
            }
        }
    }
    // epilogue: row m = m0 + wave*16 + kg*4 + r, col n = n0 + j*16 + lr
    #pragma unroll
    for (int j = 0; j < 4; j++) {
        int n = n0 + j * 16 + lr;
        float bv = bias ? bias[n] : 0.f;
        #pragma unroll
        for (int r = 0; r < 4; r++) {
            int m = m0 + wave * 16 + kg * 4 + r;
            float v = acc[j][r] + bv;
            if (MODE == 1) ((float*)Cv)[(size_t)m * ldc + n] += v;
            if (MODE == 2) {
                v = 0.5f * v * (1.f + erff(v * 0.70710678118654752f));
                ((unsigned short*)Cv)[(size_t)m * ldc + n] = f2bf(v);
            }
            if (MODE == 3) {
                int b = m / 196, s = m - b * 196 + 1;   // token remap
                ((float*)Cv)[((size_t)(b * S + s)) * E + n] = v + pos[(size_t)s * E + n];
            }
            if (MODE == 4) ((unsigned short*)Cv)[(size_t)m * ldc + n] = f2bf(v);
        }
    }
}

static inline int s64_grid(int MT, int NT) { return ((MT + 7) / 8) * 8 * NT; }

// ---------------------------------------------------------------------------
// MFMA flash attention. One block per (b,h); 4 waves, each takes Q-tiles
// round-robin. qkv bf16 [MS][768]; out bf16 [MS][256].
__global__ __launch_bounds__(256) void attn_kernel(
        const unsigned short* __restrict__ qkv, unsigned short* __restrict__ o) {
    int b = blockIdx.x >> 4, hh = blockIdx.x & 15;
    __shared__ unsigned short Qs[208][32];
    __shared__ unsigned short Ks[208][32];
    __shared__ unsigned short Vt[16][224];
    __shared__ unsigned short Ps[4][16][224];
    int tid = threadIdx.x, wave = tid >> 6, lane = tid & 63;
    int lr = lane & 15, kg = lane >> 4;
    short8 z8 = {};
    if (tid < 208) {
        if (tid < 197) {
            size_t row = (size_t)(b * S + tid) * 768 + hh * 16;
            *(short8*)&Qs[tid][0] = *(const short8*)&qkv[row];
            *(short8*)&Qs[tid][8] = *(const short8*)&qkv[row + 8];
            *(short8*)&Ks[tid][0] = *(const short8*)&qkv[row + 256];
            *(short8*)&Ks[tid][8] = *(const short8*)&qkv[row + 264];
            union { short8 v8[2]; unsigned short u[16]; } vv;
            vv.v8[0] = *(const short8*)&qkv[row + 512];
            vv.v8[1] = *(const short8*)&qkv[row + 520];
            #pragma unroll
            for (int d = 0; d < 16; d++) Vt[d][tid] = vv.u[d];
        } else {
            *(short8*)&Qs[tid][0] = z8; *(short8*)&Qs[tid][8] = z8;
            *(short8*)&Ks[tid][0] = z8; *(short8*)&Ks[tid][8] = z8;
            #pragma unroll
            for (int d = 0; d < 16; d++) Vt[d][tid] = 0;
        }
        *(short8*)&Qs[tid][16] = z8; *(short8*)&Qs[tid][24] = z8;
        *(short8*)&Ks[tid][16] = z8; *(short8*)&Ks[tid][24] = z8;
    } else if (tid < 224) {
        #pragma unroll
        for (int d = 0; d < 16; d++) Vt[d][tid] = 0;
    }
    {   // zero P pad cols [208,224) of this wave's scratch
        short4v z4 = {};
        *(short4v*)&Ps[wave][lane >> 2][208 + (lane & 3) * 4] = z4;
    }
    __syncthreads();
    const f32x4 zf = {0.f, 0.f, 0.f, 0.f};
    for (int it = wave; it < 13; it += 4) {
        short8 qa = *(short8*)&Qs[it * 16 + lr][kg * 8];
        f32x4 sc[13];
        #pragma unroll
        for (int j = 0; j < 13; j++) {
            short8 kb = *(short8*)&Ks[j * 16 + lr][kg * 8];
            sc[j] = __builtin_amdgcn_mfma_f32_16x16x32_bf16(qa, kb, zf, 0, 0, 0);
        }
        float m[4] = {-1e30f, -1e30f, -1e30f, -1e30f};
        #pragma unroll
        for (int j = 0; j < 13; j++) {
            if (j * 16 + lr < 197) {
                #pragma unroll
                for (int r = 0; r < 4; r++) m[r] = fmaxf(m[r], sc[j][r]);
            }
        }
        #pragma unroll
        for (int off = 1; off < 16; off <<= 1)
            #pragma unroll
            for (int r = 0; r < 4; r++) m[r] = fmaxf(m[r], __shfl_xor(m[r], off, 64));
        float l[4] = {0.f, 0.f, 0.f, 0.f};
        #pragma unroll
        for (int j = 0; j < 13; j++) {
            bool valid = (j * 16 + lr) < 197;
            #pragma unroll
            for (int r = 0; r < 4; r++) {
                float p = valid ? __expf((sc[j][r] - m[r]) * 0.25f) : 0.f;
                l[r] += p;
                Ps[wave][kg * 4 + r][j * 16 + lr] = f2bf(p);
            }
        }
        #pragma unroll
        for (int off = 1; off < 16; off <<= 1)
            #pragma unroll
            for (int r = 0; r < 4; r++) l[r] += __shfl_xor(l[r], off, 64);
        f32x4 oa = zf;
        #pragma unroll
        for (int k0 = 0; k0 < 224; k0 += 32) {
            short8 pa = *(short8*)&Ps[wave][lr][k0 + kg * 8];
            short8 vb = *(short8*)&Vt[lr][k0 + kg * 8];
            oa = __builtin_amdgcn_mfma_f32_16x16x32_bf16(pa, vb, oa, 0, 0, 0);
        }
        #pragma unroll
        for (int r = 0; r < 4; r++) {
            int q = it * 16 + kg * 4 + r;
            if (q < 197)
                o[((size_t)(b * S + q)) * 256 + hh * 16 + lr] = f2bf(oa[r] / l[r]);
        }
    }
}

// ---------------------------------------------------------------------------
// Final LN on cls token + head GEMM. One block per sample.
__global__ __launch_bounds__(256) void head_kernel(
        const float* __restrict__ h, const float* __restrict__ g,
        const float* __restrict__ bb, const float* __restrict__ Wh,
        const float* __restrict__ bh, float* __restrict__ out) {
    __shared__ float red4[4];
    __shared__ float xs[256];
    int b = blockIdx.x, e = threadIdx.x;
    float v = h[((size_t)(b * S)) * E + e];
    float mean = block_reduce(v, red4, 0) * (1.f / 256.f);
    float d = v - mean;
    float var = block_reduce(d * d, red4, 0) * (1.f / 256.f);
    float xn = d * rsqrtf(var + 1e-5f) * g[e] + bb[e];
    xs[e] = xn;
    __syncthreads();
    for (int n = 0; n < 8; n++) {
        float s = block_reduce(xs[e] * Wh[(size_t)n * 256 + e], red4, 0);
        if (e == 0) out[b * 8 + n] = s + bh[n];
    }
}

// ---------------------------------------------------------------------------
extern "C" void kernel_launch(void* const* d_in, const int* in_sizes, int n_in,
                              void* d_out, int out_size, void* d_ws, size_t ws_size,
                              hipStream_t stream) {
    const float* x      = (const float*)d_in[0];
    const float* W_patch= (const float*)d_in[1];
    const float* b_patch= (const float*)d_in[2];
    const float* cls_tok= (const float*)d_in[3];
    const float* pos_emb= (const float*)d_in[4];
    const float* Wkl = (const float*)d_in[5];   const float* bkl = (const float*)d_in[6];
    const float* Wvl = (const float*)d_in[7];   const float* bvl = (const float*)d_in[8];
    const float* Wkr = (const float*)d_in[9];   const float* bkr = (const float*)d_in[10];
    const float* Wvr = (const float*)d_in[11];  const float* bvr = (const float*)d_in[12];
    const float* Wkt = (const float*)d_in[13];  const float* bkt = (const float*)d_in[14];
    const float* Wvt = (const float*)d_in[15];  const float* bvt = (const float*)d_in[16];
    const float* ln1_g = (const float*)d_in[17]; const float* ln1_b = (const float*)d_in[18];
    const float* Wqkv  = (const float*)d_in[19]; const float* bqkv  = (const float*)d_in[20];
    const float* Wo    = (const float*)d_in[21]; const float* bo    = (const float*)d_in[22];
    const float* ln2_g = (const float*)d_in[23]; const float* ln2_b = (const float*)d_in[24];
    const float* W1 = (const float*)d_in[25];   const float* b1 = (const float*)d_in[26];
    const float* W2 = (const float*)d_in[27];   const float* b2 = (const float*)d_in[28];
    const float* lnf_g = (const float*)d_in[29]; const float* lnf_b = (const float*)d_in[30];
    const float* W_head = (const float*)d_in[31]; const float* b_head = (const float*)d_in[32];

    // Workspace layout (total 73,531,392 B):
    //   regionB  19,660,800 B  — time-shared: {h0+ragws, qkb+ob, ff}
    //   h1        6,553,600 B  — persistent fp32 residual stream
    //   xnb       3,276,800 B  — bf16 LN output
    //   wall     44,040,192 B  — ALL layers' weights in bf16 (converted once)
    char* p = (char*)d_ws;
    unsigned short* regionB = (unsigned short*)p; p += (size_t)MP * 1536 * 2;
    float* h1 = (float*)p;                        p += (size_t)MP * 256 * 4;
    unsigned short* xnb = (unsigned short*)p;     p += (size_t)MP * 256 * 2;
    unsigned short* wall = (unsigned short*)p;
    // aliases inside regionB (disjoint in time or space — see per-phase notes)
    unsigned short* qkb = regionB;                          // bytes [0, 9.83M)   qkv->attn
    unsigned short* ob  = regionB + 5242880;                // bytes [10.49M, 13.76M) attn->proj
    unsigned short* ff  = regionB;                          // bytes [0, 19.66M)  FF1->FF2
    float* h0 = (float*)regionB;                            // bytes [0, 6.55M)   pre-loop
    unsigned short* wp_b = ob;                              // pre-loop Wp bf16 temp
    float* ragws = (float*)((char*)regionB + 7340032);      // pre-loop rag scratch
    float* M    = ragws;              // 32*256
    float* Ul   = ragws + 8192;
    float* Ur   = ragws + 2 * 8192;
    float* Ut   = ragws + 3 * 8192;
    float* cl   = ragws + 4 * 8192;   // 32
    float* cr   = cl + 32;
    float* ct   = cl + 64;
    float* fbuf = cl + 96;            // 30*256

    // ---- convert ALL transformer weights once ----
    convert_w_all_kernel<<<21504, 256, 0, stream>>>(Wqkv, Wo, W1, W2, wall);

    // ---- patch embedding as MFMA GEMM ----
    convert_kernel<<<128, 256, 0, stream>>>(W_patch, wp_b);
    patchify_kernel<<<NPAT, 256, 0, stream>>>(x, xnb);
    cls_pos_kernel<<<Bz, 256, 0, stream>>>(cls_tok, pos_emb, h0);
    gemm_s64<3><<<s64_grid(98, 4), 256, 0, stream>>>(
        xnb, 256, wp_b, 256, b_patch, h0, 256, 256, 98, 4, pos_emb);

    // ---- rag mixer (parallelized, fp32) ----
    means_kernel<<<Bz, 256, 0, stream>>>(h0, M);
    uvec_kernel<<<Bz, 256, 0, stream>>>(M, Wkl, bkl, Wkr, bkr, Wkt, bkt,
                                        Ul, Ur, Ut, cl, cr, ct);
    rag_score_kernel<<<(Bz - 2) * 4, 256, 0, stream>>>(
        h0, M, Ul, Ur, Ut, cl, cr, ct, Wvl, bvl, Wvr, bvr, Wvt, bvt, fbuf);
    rag_outer_kernel<<<(Bz - 2) * S, 256, 0, stream>>>(fbuf, M, h1);
    copy_edges<<<(2 * S * E + 255) / 256, 256, 0, stream>>>(h0, h1);

    for (int l = 0; l < Ln; l++) {
        const unsigned short* wqkv_b = wall + (size_t)l * WLSTRIDE;
        const unsigned short* wo_b   = wqkv_b + 196608;
        const unsigned short* w1_b   = wqkv_b + 262144;
        const unsigned short* w2_b   = wqkv_b + 1048576;
        ln_kernel<<<MS / 4, 256, 0, stream>>>(h1, xnb, ln1_g + l * E, ln1_b + l * E);
        gemm_s64<4><<<s64_grid(100, 12), 256, 0, stream>>>(
            xnb, 256, wqkv_b, 256, bqkv + l * 768, qkb, 768, 256, 100, 12, nullptr);
        attn_kernel<<<Bz * Hn, 256, 0, stream>>>(qkb, ob);
        gemm_s64<1><<<s64_grid(100, 4), 256, 0, stream>>>(
            ob, 256, wo_b, 256, bo + l * 256, h1, 256, 256, 100, 4, nullptr);
        ln_kernel<<<MS / 4, 256, 0, stream>>>(h1, xnb, ln2_g + l * E, ln2_b + l * E);
        for (int c = 0; c < 2; c++) {
            gemm_s64<2><<<s64_grid(100, 24), 256, 0, stream>>>(
                xnb, 256, w1_b + (size_t)c * 1536 * 256, 256, b1 + l * Fd + c * 1536,
                ff, 1536, 256, 100, 24, nullptr);
            gemm_s64<1><<<s64_grid(100, 4), 256, 0, stream>>>(
                ff, 1536, w2_b + c * 1536, 3072, (c == 0 ? b2 + l * 256 : nullptr),
                h1, 256, 1536, 100, 4, nullptr);
        }
    }
    head_kernel<<<Bz, 256, 0, stream>>>(h1, lnf_g, lnf_b, W_head, b_head, (float*)d_out);
}

// Round 9
// 1660.934 us; speedup vs baseline: 1.1401x; 1.0526x over previous
//
#include <hip/hip_runtime.h>
#include <hip/hip_bf16.h>
#include <math.h>

// Problem constants
constexpr int Bz  = 32;
constexpr int S   = 197;
constexpr int E   = 256;
constexpr int Hn  = 16;
constexpr int HD  = 16;
constexpr int Fd  = 3072;
constexpr int Ln  = 12;
constexpr int MS  = Bz * S;         // 6304 tokens
constexpr int MP  = 6400;           // padded: 100 m-tiles of 64 / 50 of 128
constexpr int NPAT = 6272;          // 32*196 patches = 98 * 64
constexpr int DVL = 50, DVR = 49, DVT = 49;
constexpr size_t WLSTRIDE = 1835008;  // bf16 weights per layer

typedef __attribute__((ext_vector_type(8))) short short8;   // 8 bf16 = 4 VGPRs
typedef __attribute__((ext_vector_type(4))) short short4v;
typedef __attribute__((ext_vector_type(4))) float f32x4;

__device__ __forceinline__ unsigned short f2bf(float f) {
    unsigned int u = __float_as_uint(f);
    u = (u + 0x7FFFu + ((u >> 16) & 1u)) >> 16;             // RNE
    return (unsigned short)u;
}

// async global->LDS, 16 B per lane. LDS dest is wave-uniform base + lane*16.
__device__ __forceinline__ void gload_lds16(const void* g, void* l) {
    __builtin_amdgcn_global_load_lds(
        (const __attribute__((address_space(1))) void*)g,
        (__attribute__((address_space(3))) void*)l, 16, 0, 0);
}

// wave reduce (64 lanes), op 0=sum 1=max
__device__ __forceinline__ float wave_reduce(float v, int op) {
    #pragma unroll
    for (int off = 32; off > 0; off >>= 1) {
        float o = __shfl_xor(v, off, 64);
        v = op ? fmaxf(v, o) : v + o;
    }
    return v;
}

// block-wide reduce (256 thr): wave shuffle + 4-slot LDS. op: 0=sum, 1=max.
__device__ __forceinline__ float block_reduce(float v, float* red4, int op) {
    v = wave_reduce(v, op);
    int w = threadIdx.x >> 6;
    if ((threadIdx.x & 63) == 0) red4[w] = v;
    __syncthreads();
    float r = op ? fmaxf(fmaxf(red4[0], red4[1]), fmaxf(red4[2], red4[3]))
                 : (red4[0] + red4[1] + red4[2] + red4[3]);
    __syncthreads();
    return r;
}

// ---------------------------------------------------------------------------
// Patchify: x (B,1,224,224) -> bf16 A[6272][256], A[b*196+q][pr*16+pc].
__global__ __launch_bounds__(256) void patchify_kernel(
        const float* __restrict__ x, unsigned short* __restrict__ Ab) {
    int pi = blockIdx.x;                 // 0..6271
    int b = pi / 196, q = pi % 196;
    int i = q / 14, j = q % 14;
    int e = threadIdx.x, pr = e >> 4, pc = e & 15;
    float v = x[((size_t)(b * 224 + i * 16 + pr)) * 224 + j * 16 + pc];
    Ab[(size_t)pi * 256 + e] = f2bf(v);
}

// cls token rows of h0
__global__ __launch_bounds__(256) void cls_pos_kernel(
        const float* __restrict__ cls, const float* __restrict__ pos,
        float* __restrict__ h0) {
    int b = blockIdx.x, e = threadIdx.x;
    h0[(size_t)(b * S) * E + e] = cls[e] + pos[e];
}

// fp32 -> bf16, 4 elems/thread
__global__ __launch_bounds__(256) void convert_kernel(
        const float* __restrict__ src, unsigned short* __restrict__ dst) {
    int i4 = (blockIdx.x * 256 + threadIdx.x) * 4;
    float4 v = *(const float4*)(src + i4);
    ushort4 o;
    o.x = f2bf(v.x); o.y = f2bf(v.y); o.z = f2bf(v.z); o.w = f2bf(v.w);
    *(ushort4*)(dst + i4) = o;
}

// ALL layers' weights fp32 -> bf16 in one dispatch. grid 21504 x 256.
__global__ __launch_bounds__(256) void convert_w_all_kernel(
        const float* __restrict__ wqkv, const float* __restrict__ wo,
        const float* __restrict__ w1, const float* __restrict__ w2,
        unsigned short* __restrict__ out) {
    size_t idx = (size_t)blockIdx.x * 256 + threadIdx.x;   // 0..5505023
    int l = (int)(idx / 458752);
    int r4 = (int)(idx % 458752) * 4;
    const float* src;
    if (r4 < 196608)       src = wqkv + (size_t)l * 196608 + r4;
    else if (r4 < 262144)  src = wo   + (size_t)l * 65536  + (r4 - 196608);
    else if (r4 < 1048576) src = w1   + (size_t)l * 786432 + (r4 - 262144);
    else                   src = w2   + (size_t)l * 786432 + (r4 - 1048576);
    float4 v = *(const float4*)src;
    ushort4 o;
    o.x = f2bf(v.x); o.y = f2bf(v.y); o.z = f2bf(v.z); o.w = f2bf(v.w);
    *(ushort4*)(out + (size_t)l * WLSTRIDE + r4) = o;
}

// ---------------------------------------------------------------------------
// rag stage 1: per-sample token means. grid 32; waves split tokens (50 iters).
__global__ __launch_bounds__(256) void means_kernel(
        const float* __restrict__ h0, float* __restrict__ M) {
    __shared__ float part[4][256];
    int b = blockIdx.x, tid = threadIdx.x, w = tid >> 6, lane = tid & 63;
    float4 a = {0.f, 0.f, 0.f, 0.f};
    for (int t = w; t < S; t += 4) {
        float4 v = *(const float4*)&h0[((size_t)(b * S + t)) * E + lane * 4];
        a.x += v.x; a.y += v.y; a.z += v.z; a.w += v.w;
    }
    *(float4*)&part[w][lane * 4] = a;
    __syncthreads();
    M[b * E + tid] = (part[0][tid] + part[1][tid] + part[2][tid] + part[3][tid])
                     * (1.f / (float)S);
}

// rag stage 2: U_x[t] = Wk_x.T @ M[t], c_x[t] = bk_x . M[t]. grid 32.
// Waves split the i-reduction (64 iters each), float4 cols per lane.
__global__ __launch_bounds__(256) void uvec_kernel(
        const float* __restrict__ M,
        const float* __restrict__ Wkl, const float* __restrict__ bkl,
        const float* __restrict__ Wkr, const float* __restrict__ bkr,
        const float* __restrict__ Wkt, const float* __restrict__ bkt,
        float* __restrict__ Ul, float* __restrict__ Ur, float* __restrict__ Ut,
        float* __restrict__ cl, float* __restrict__ cr, float* __restrict__ ct) {
    __shared__ float p0[4][256], p1[4][256], p2[4][256], red4[4];
    int t = blockIdx.x, tid = threadIdx.x, w = tid >> 6, lane = tid & 63;
    const float* mt = M + t * E;
    float4 a0 = {0,0,0,0}, a1 = {0,0,0,0}, a2 = {0,0,0,0};
    for (int i = w * 64; i < w * 64 + 64; i++) {
        float mi = mt[i];
        float4 v0 = *(const float4*)&Wkl[(size_t)i * 256 + lane * 4];
        float4 v1 = *(const float4*)&Wkr[(size_t)i * 256 + lane * 4];
        float4 v2 = *(const float4*)&Wkt[(size_t)i * 256 + lane * 4];
        a0.x += v0.x * mi; a0.y += v0.y * mi; a0.z += v0.z * mi; a0.w += v0.w * mi;
        a1.x += v1.x * mi; a1.y += v1.y * mi; a1.z += v1.z * mi; a1.w += v1.w * mi;
        a2.x += v2.x * mi; a2.y += v2.y * mi; a2.z += v2.z * mi; a2.w += v2.w * mi;
    }
    *(float4*)&p0[w][lane * 4] = a0;
    *(float4*)&p1[w][lane * 4] = a1;
    *(float4*)&p2[w][lane * 4] = a2;
    __syncthreads();
    Ul[t * E + tid] = p0[0][tid] + p0[1][tid] + p0[2][tid] + p0[3][tid];
    Ur[t * E + tid] = p1[0][tid] + p1[1][tid] + p1[2][tid] + p1[3][tid];
    Ut[t * E + tid] = p2[0][tid] + p2[1][tid] + p2[2][tid] + p2[3][tid];
    float me = mt[tid];
    float c0 = block_reduce(bkl[tid] * me, red4, 0);
    float c1 = block_reduce(bkr[tid] * me, red4, 0);
    float c2 = block_reduce(bkt[tid] * me, red4, 0);
    if (tid == 0) { cl[t] = c0; cr[t] = c1; ct[t] = c2; }
}

// rag stage 3: scores+softmax+xbar+f for one (t, branch). grid 120, 256 thr.
// Both reduction loops wave-split (50 iters/wave).
__global__ __launch_bounds__(256) void rag_score_kernel(
        const float* __restrict__ h0, const float* __restrict__ M,
        const float* __restrict__ Ul, const float* __restrict__ Ur,
        const float* __restrict__ Ut,
        const float* __restrict__ cl, const float* __restrict__ cr,
        const float* __restrict__ ct,
        const float* __restrict__ Wvl, const float* __restrict__ bvl,
        const float* __restrict__ Wvr, const float* __restrict__ bvr,
        const float* __restrict__ Wvt, const float* __restrict__ bvt,
        float* __restrict__ fbuf) {
    int t = blockIdx.x >> 2, br = blockIdx.x & 3;
    const float* xsrc; const float* u; float c;
    const float* Wv; const float* bv; int dv, fo;
    if (br == 0)      { xsrc = h0 + (size_t)t * S * E;       u = Ul + (t+1)*E; c = cl[t+1]; Wv = Wvl; bv = bvl; dv = DVL; fo = 0; }
    else if (br == 1) { xsrc = h0 + (size_t)(t+1) * S * E;   u = Ut + t*E;     c = ct[t];   Wv = Wvt; bv = bvt; dv = DVT; fo = DVL; }
    else if (br == 2) { xsrc = h0 + (size_t)(t+1) * S * E;   u = Ut + (t+2)*E; c = ct[t+2]; Wv = Wvt; bv = bvt; dv = DVT; fo = DVL + DVT; }
    else              { xsrc = h0 + (size_t)(t+2) * S * E;   u = Ur + (t+1)*E; c = cr[t+1]; Wv = Wvr; bv = bvr; dv = DVR; fo = DVL + 2*DVT; }
    __shared__ float us[256], sc[200], xbar[256], part[4][256], red4[4];
    int tid = threadIdx.x, w = tid >> 6, lane = tid & 63;
    us[tid] = u[tid];
    __syncthreads();
    float4 u4 = *(float4*)&us[lane * 4];
    for (int s = w; s < S; s += 4) {
        float4 x4 = *(const float4*)&xsrc[(size_t)s * E + lane * 4];
        float p = x4.x*u4.x + x4.y*u4.y + x4.z*u4.z + x4.w*u4.w;
        p = wave_reduce(p, 0);
        if (lane == 0) sc[s] = (p + c) * 0.0625f;     // 1/sqrt(E)
    }
    __syncthreads();
    float v = (tid < S) ? sc[tid] : -1e30f;
    float mx = block_reduce(v, red4, 1);
    float ex = (tid < S) ? expf(v - mx) : 0.f;
    float dn = block_reduce(ex, red4, 0);
    if (tid < S) sc[tid] = ex / dn;
    __syncthreads();
    // xbar: wave-split over tokens, float4 cols per lane, LDS combine
    float4 pa = {0.f, 0.f, 0.f, 0.f};
    for (int s = w; s < S; s += 4) {
        float a = sc[s];
        float4 x4 = *(const float4*)&xsrc[(size_t)s * E + lane * 4];
        pa.x += a * x4.x; pa.y += a * x4.y; pa.z += a * x4.z; pa.w += a * x4.w;
    }
    *(float4*)&part[w][lane * 4] = pa;
    __syncthreads();
    xbar[tid] = part[0][tid] + part[1][tid] + part[2][tid] + part[3][tid];
    __syncthreads();
    float4 xb4 = *(float4*)&xbar[lane * 4];
    for (int d = w; d < dv; d += 4) {
        float4 w4 = *(const float4*)&Wv[(size_t)d * E + lane * 4];
        float p = w4.x*xb4.x + w4.y*xb4.y + w4.z*xb4.z + w4.w*xb4.w;
        p = wave_reduce(p, 0);
        if (lane == 0) fbuf[t * 256 + fo + d] = p + bv[d];
    }
}

// rag stage 4: outer product h1[t+1][s][:] = f[t][s] * M[t+1][:]
__global__ __launch_bounds__(256) void rag_outer_kernel(
        const float* __restrict__ fbuf, const float* __restrict__ M,
        float* __restrict__ h1) {
    int bid = blockIdx.x;                    // 0..30*197-1
    int t = bid / S, s = bid % S;
    float f = fbuf[t * 256 + s];             // uniform
    int e = threadIdx.x;
    h1[((size_t)((t + 1) * S + s)) * E + e] = f * M[(t + 1) * E + e];
}

// copy h0 samples 0 and 31 into h1
__global__ __launch_bounds__(256) void copy_edges(const float* __restrict__ h0,
                                                  float* __restrict__ h1) {
    int i = blockIdx.x * 256 + threadIdx.x;
    int n = S * E;
    if (i < n) h1[i] = h0[i];
    else if (i < 2 * n) {
        int j = i - n;
        size_t o = (size_t)31 * S * E + j;
        h1[o] = h0[o];
    }
}

// ---------------------------------------------------------------------------
// LayerNorm over E=256: wave per token, float4, shuffle-only. grid MS/4.
__global__ __launch_bounds__(256) void ln_kernel(const float* __restrict__ in,
                                                 unsigned short* __restrict__ out,
                                                 const float* __restrict__ g,
                                                 const float* __restrict__ b) {
    int w = threadIdx.x >> 6, lane = threadIdx.x & 63;
    int tok = blockIdx.x * 4 + w;
    const float* row = in + (size_t)tok * E;
    float4 v = *(const float4*)&row[lane * 4];
    float mean = wave_reduce(v.x + v.y + v.z + v.w, 0) * (1.f / 256.f);
    float dx = v.x - mean, dy = v.y - mean, dz = v.z - mean, dw = v.w - mean;
    float var = wave_reduce(dx*dx + dy*dy + dz*dz + dw*dw, 0) * (1.f / 256.f);
    float inv = rsqrtf(var + 1e-5f);
    float4 gg = *(const float4*)&g[lane * 4];
    float4 bb = *(const float4*)&b[lane * 4];
    ushort4 o;
    o.x = f2bf(dx * inv * gg.x + bb.x);
    o.y = f2bf(dy * inv * gg.y + bb.y);
    o.z = f2bf(dz * inv * gg.z + bb.z);
    o.w = f2bf(dw * inv * gg.w + bb.w);
    *(ushort4*)&out[(size_t)tok * E + lane * 4] = o;
}

// ---------------------------------------------------------------------------
// 64x64-tile bf16 MFMA GEMM. BK=64, double-buffered (32 KB LDS), XCD-swizzled
// flat grid: mt=(id&7)+8*(id/(8*NT)), nt=(id>>3)%NT. Blocks mt>=MT exit.
// MODE 1: fp32 += (+bias) | MODE 3: patch epilogue | MODE 4: bf16 store
template <int MODE>
__global__ __launch_bounds__(256) void gemm_s64(
        const unsigned short* __restrict__ A, int lda,
        const unsigned short* __restrict__ W, int ldw,
        const float* __restrict__ bias,
        void* __restrict__ Cv, int ldc, int K, int MT, int NT,
        const float* __restrict__ pos) {
    __shared__ unsigned short As[2 * 64 * 64];
    __shared__ unsigned short Bs[2 * 64 * 64];
    const int id = blockIdx.x;
    const int mt = (id & 7) + 8 * (id / (8 * NT));
    const int nt = (id >> 3) % NT;
    if (mt >= MT) return;
    const int m0 = mt * 64, n0 = nt * 64;
    const int tid = threadIdx.x, wave = tid >> 6, lane = tid & 63;
    const int lr = lane & 15, kg = lane >> 4;
    const int srow = wave * 16 + (lane >> 3);           // +q*8
    const int scol = ((lane & 7) ^ (lane >> 3)) * 8;    // swizzled granule col
    auto stage = [&](int bb, int k0) {
        #pragma unroll
        for (int q = 0; q < 2; q++) {
            gload_lds16(&A[(size_t)(m0 + srow + q * 8) * lda + k0 + scol],
                        &As[bb * 4096 + (wave * 16 + q * 8) * 64]);
            gload_lds16(&W[(size_t)(n0 + srow + q * 8) * ldw + k0 + scol],
                        &Bs[bb * 4096 + (wave * 16 + q * 8) * 64]);
        }
    };
    const int nIter = K >> 6;
    stage(0, 0);
    f32x4 acc[4] = {};
    for (int i = 0; i < nIter; i++) {
        __syncthreads();
        if (i + 1 < nIter) stage((i + 1) & 1, (i + 1) * 64);
        const int bb = i & 1;
        #pragma unroll
        for (int h = 0; h < 2; h++) {
            const int sw = ((h * 4 + kg) ^ (lr & 7)) * 8;
            short8 af = *(short8*)&As[bb * 4096 + (wave * 16 + lr) * 64 + sw];
            #pragma unroll
            for (int j = 0; j < 4; j++) {
                short8 bf = *(short8*)&Bs[bb * 4096 + (j * 16 + lr) * 64 + sw];
                acc[j] = __builtin_amdgcn_mfma_f32_16x16x32_bf16(af, bf, acc[j], 0, 0, 0);
            }
        }
    }
    #pragma unroll
    for (int j = 0; j < 4; j++) {
        int n = n0 + j * 16 + lr;
        float bv = bias ? bias[n] : 0.f;
        #pragma unroll
        for (int r = 0; r < 4; r++) {
            int m = m0 + wave * 16 + kg * 4 + r;
            float v = acc[j][r] + bv;
            if (MODE == 1) ((float*)Cv)[(size_t)m * ldc + n] += v;
            if (MODE == 3) {
                int b = m / 196, s = m - b * 196 + 1;   // token remap
                ((float*)Cv)[((size_t)(b * S + s)) * E + n] = v + pos[(size_t)s * E + n];
            }
            if (MODE == 4) ((unsigned short*)Cv)[(size_t)m * ldc + n] = f2bf(v);
        }
    }
}

// ---------------------------------------------------------------------------
// 128x128-tile bf16 MFMA GEMM, BK=64, double-buffered (64 KB LDS), XCD-
// swizzled flat grid. 4 waves x (64x64), MFMA:ds_read = 16:8.
// MODE 2: gelu -> bf16 store
template <int MODE>
__global__ __launch_bounds__(256) void gemm_s128(
        const unsigned short* __restrict__ A, int lda,
        const unsigned short* __restrict__ W, int ldw,
        const float* __restrict__ bias,
        void* __restrict__ Cv, int ldc, int K, int MT, int NT) {
    __shared__ unsigned short As[2 * 128 * 64];
    __shared__ unsigned short Bs[2 * 128 * 64];
    const int id = blockIdx.x;
    const int mt = (id & 7) + 8 * (id / (8 * NT));
    const int nt = (id >> 3) % NT;
    if (mt >= MT) return;
    const int m0 = mt * 128, n0 = nt * 128;
    const int tid = threadIdx.x, wave = tid >> 6, lane = tid & 63;
    const int wm = (wave >> 1) * 64, wn = (wave & 1) * 64;
    const int lr = lane & 15, kg = lane >> 4;
    const int srow = wave * 32 + (lane >> 3);
    const int scol = ((lane & 7) ^ (lane >> 3)) * 8;
    auto stage = [&](int bb, int k0) {
        #pragma unroll
        for (int q = 0; q < 4; q++) {
            gload_lds16(&A[(size_t)(m0 + srow + q * 8) * lda + k0 + scol],
                        &As[bb * 8192 + (wave * 4 + q) * 512]);
            gload_lds16(&W[(size_t)(n0 + srow + q * 8) * ldw + k0 + scol],
                        &Bs[bb * 8192 + (wave * 4 + q) * 512]);
        }
    };
    const int nIter = K >> 6;
    stage(0, 0);
    f32x4 acc[4][4] = {};
    for (int i = 0; i < nIter; i++) {
        __syncthreads();
        if (i + 1 < nIter) stage((i + 1) & 1, (i + 1) * 64);
        const int bb = i & 1;
        #pragma unroll
        for (int h = 0; h < 2; h++) {
            const int sw = ((h * 4 + kg) ^ (lr & 7)) * 8;
            short8 af[4], bfr[4];
            #pragma unroll
            for (int i2 = 0; i2 < 4; i2++) af[i2]  = *(short8*)&As[bb * 8192 + (wm + i2 * 16 + lr) * 64 + sw];
            #pragma unroll
            for (int j = 0; j < 4; j++) bfr[j] = *(short8*)&Bs[bb * 8192 + (wn + j * 16 + lr) * 64 + sw];
            #pragma unroll
            for (int i2 = 0; i2 < 4; i2++)
                #pragma unroll
                for (int j = 0; j < 4; j++)
                    acc[i2][j] = __builtin_amdgcn_mfma_f32_16x16x32_bf16(af[i2], bfr[j], acc[i2][j], 0, 0, 0);
        }
    }
    #pragma unroll
    for (int j = 0; j < 4; j++) {
        int n = n0 + wn + j * 16 + lr;
        float bv = bias ? bias[n] : 0.f;
        #pragma unroll
        for (int i = 0; i < 4; i++) {
            #pragma unroll
            for (int r = 0; r < 4; r++) {
                size_t m = (size_t)(m0 + wm + i * 16 + kg * 4 + r);
                float v = acc[i][j][r] + bv;
                if (MODE == 2) {
                    v = 0.5f * v * (1.f + erff(v * 0.70710678118654752f));
                    ((unsigned short*)Cv)[m * ldc + n] = f2bf(v);
                }
            }
        }
    }
}

static inline int sg(int MT, int NT) { return ((MT + 7) / 8) * 8 * NT; }

// ---------------------------------------------------------------------------
// MFMA flash attention. One block per (b,h); 4 waves, each takes Q-tiles
// round-robin. qkv bf16 [MS][768]; out bf16 [MS][256].
__global__ __launch_bounds__(256) void attn_kernel(
        const unsigned short* __restrict__ qkv, unsigned short* __restrict__ o) {
    int b = blockIdx.x >> 4, hh = blockIdx.x & 15;
    __shared__ unsigned short Qs[208][32];
    __shared__ unsigned short Ks[208][32];
    __shared__ unsigned short Vt[16][224];
    __shared__ unsigned short Ps[4][16][224];
    int tid = threadIdx.x, wave = tid >> 6, lane = tid & 63;
    int lr = lane & 15, kg = lane >> 4;
    short8 z8 = {};
    if (tid < 208) {
        if (tid < 197) {
            size_t row = (size_t)(b * S + tid) * 768 + hh * 16;
            *(short8*)&Qs[tid][0] = *(const short8*)&qkv[row];
            *(short8*)&Qs[tid][8] = *(const short8*)&qkv[row + 8];
            *(short8*)&Ks[tid][0] = *(const short8*)&qkv[row + 256];
            *(short8*)&Ks[tid][8] = *(const short8*)&qkv[row + 264];
            union { short8 v8[2]; unsigned short u[16]; } vv;
            vv.v8[0] = *(const short8*)&qkv[row + 512];
            vv.v8[1] = *(const short8*)&qkv[row + 520];
            #pragma unroll
            for (int d = 0; d < 16; d++) Vt[d][tid] = vv.u[d];
        } else {
            *(short8*)&Qs[tid][0] = z8; *(short8*)&Qs[tid][8] = z8;
            *(short8*)&Ks[tid][0] = z8; *(short8*)&Ks[tid][8] = z8;
            #pragma unroll
            for (int d = 0; d < 16; d++) Vt[d][tid] = 0;
        }
        *(short8*)&Qs[tid][16] = z8; *(short8*)&Qs[tid][24] = z8;
        *(short8*)&Ks[tid][16] = z8; *(short8*)&Ks[tid][24] = z8;
    } else if (tid < 224) {
        #pragma unroll
        for (int d = 0; d < 16; d++) Vt[d][tid] = 0;
    }
    {   // zero P pad cols [208,224) of this wave's scratch
        short4v z4 = {};
        *(short4v*)&Ps[wave][lane >> 2][208 + (lane & 3) * 4] = z4;
    }
    __syncthreads();
    const f32x4 zf = {0.f, 0.f, 0.f, 0.f};
    for (int it = wave; it < 13; it += 4) {
        short8 qa = *(short8*)&Qs[it * 16 + lr][kg * 8];
        f32x4 sc[13];
        #pragma unroll
        for (int j = 0; j < 13; j++) {
            short8 kb = *(short8*)&Ks[j * 16 + lr][kg * 8];
            sc[j] = __builtin_amdgcn_mfma_f32_16x16x32_bf16(qa, kb, zf, 0, 0, 0);
        }
        float m[4] = {-1e30f, -1e30f, -1e30f, -1e30f};
        #pragma unroll
        for (int j = 0; j < 13; j++) {
            if (j * 16 + lr < 197) {
                #pragma unroll
                for (int r = 0; r < 4; r++) m[r] = fmaxf(m[r], sc[j][r]);
            }
        }
        #pragma unroll
        for (int off = 1; off < 16; off <<= 1)
            #pragma unroll
            for (int r = 0; r < 4; r++) m[r] = fmaxf(m[r], __shfl_xor(m[r], off, 64));
        float l[4] = {0.f, 0.f, 0.f, 0.f};
        #pragma unroll
        for (int j = 0; j < 13; j++) {
            bool valid = (j * 16 + lr) < 197;
            #pragma unroll
            for (int r = 0; r < 4; r++) {
                float p = valid ? __expf((sc[j][r] - m[r]) * 0.25f) : 0.f;
                l[r] += p;
                Ps[wave][kg * 4 + r][j * 16 + lr] = f2bf(p);
            }
        }
        #pragma unroll
        for (int off = 1; off < 16; off <<= 1)
            #pragma unroll
            for (int r = 0; r < 4; r++) l[r] += __shfl_xor(l[r], off, 64);
        f32x4 oa = zf;
        #pragma unroll
        for (int k0 = 0; k0 < 224; k0 += 32) {
            short8 pa = *(short8*)&Ps[wave][lr][k0 + kg * 8];
            short8 vb = *(short8*)&Vt[lr][k0 + kg * 8];
            oa = __builtin_amdgcn_mfma_f32_16x16x32_bf16(pa, vb, oa, 0, 0, 0);
        }
        #pragma unroll
        for (int r = 0; r < 4; r++) {
            int q = it * 16 + kg * 4 + r;
            if (q < 197)
                o[((size_t)(b * S + q)) * 256 + hh * 16 + lr] = f2bf(oa[r] / l[r]);
        }
    }
}

// ---------------------------------------------------------------------------
// Final LN on cls token + head GEMM. One block per sample.
__global__ __launch_bounds__(256) void head_kernel(
        const float* __restrict__ h, const float* __restrict__ g,
        const float* __restrict__ bb, const float* __restrict__ Wh,
        const float* __restrict__ bh, float* __restrict__ out) {
    __shared__ float red4[4];
    __shared__ float xs[256];
    int b = blockIdx.x, e = threadIdx.x;
    float v = h[((size_t)(b * S)) * E + e];
    float mean = block_reduce(v, red4, 0) * (1.f / 256.f);
    float d = v - mean;
    float var = block_reduce(d * d, red4, 0) * (1.f / 256.f);
    float xn = d * rsqrtf(var + 1e-5f) * g[e] + bb[e];
    xs[e] = xn;
    __syncthreads();
    for (int n = 0; n < 8; n++) {
        float s = block_reduce(xs[e] * Wh[(size_t)n * 256 + e], red4, 0);
        if (e == 0) out[b * 8 + n] = s + bh[n];
    }
}

// ---------------------------------------------------------------------------
extern "C" void kernel_launch(void* const* d_in, const int* in_sizes, int n_in,
                              void* d_out, int out_size, void* d_ws, size_t ws_size,
                              hipStream_t stream) {
    const float* x      = (const float*)d_in[0];
    const float* W_patch= (const float*)d_in[1];
    const float* b_patch= (const float*)d_in[2];
    const float* cls_tok= (const float*)d_in[3];
    const float* pos_emb= (const float*)d_in[4];
    const float* Wkl = (const float*)d_in[5];   const float* bkl = (const float*)d_in[6];
    const float* Wvl = (const float*)d_in[7];   const float* bvl = (const float*)d_in[8];
    const float* Wkr = (const float*)d_in[9];   const float* bkr = (const float*)d_in[10];
    const float* Wvr = (const float*)d_in[11];  const float* bvr = (const float*)d_in[12];
    const float* Wkt = (const float*)d_in[13];  const float* bkt = (const float*)d_in[14];
    const float* Wvt = (const float*)d_in[15];  const float* bvt = (const float*)d_in[16];
    const float* ln1_g = (const float*)d_in[17]; const float* ln1_b = (const float*)d_in[18];
    const float* Wqkv  = (const float*)d_in[19]; const float* bqkv  = (const float*)d_in[20];
    const float* Wo    = (const float*)d_in[21]; const float* bo    = (const float*)d_in[22];
    const float* ln2_g = (const float*)d_in[23]; const float* ln2_b = (const float*)d_in[24];
    const float* W1 = (const float*)d_in[25];   const float* b1 = (const float*)d_in[26];
    const float* W2 = (const float*)d_in[27];   const float* b2 = (const float*)d_in[28];
    const float* lnf_g = (const float*)d_in[29]; const float* lnf_b = (const float*)d_in[30];
    const float* W_head = (const float*)d_in[31]; const float* b_head = (const float*)d_in[32];

    // Workspace layout — ws_size is 256 MiB (fillBuffer poison = 262144 KB),
    // so no aliasing needed. Total ~113 MB.
    char* p = (char*)d_ws;
    float* h0 = (float*)p;                    p += (size_t)MP * 256 * 4;
    float* h1 = (float*)p;                    p += (size_t)MP * 256 * 4;
    unsigned short* qkb = (unsigned short*)p; p += (size_t)MP * 768 * 2;
    unsigned short* xnb = (unsigned short*)p; p += (size_t)MP * 256 * 2;
    unsigned short* ob  = (unsigned short*)p; p += (size_t)MP * 256 * 2;
    unsigned short* ff  = (unsigned short*)p; p += (size_t)MP * 3072 * 2;
    unsigned short* wpb = (unsigned short*)p; p += (size_t)65536 * 2;
    float* ragws = (float*)p;                 p += (size_t)40960 * 4;
    unsigned short* wall = (unsigned short*)p;
    float* M    = ragws;              // 32*256
    float* Ul   = ragws + 8192;
    float* Ur   = ragws + 2 * 8192;
    float* Ut   = ragws + 3 * 8192;
    float* cl   = ragws + 4 * 8192;   // 32
    float* cr   = cl + 32;
    float* ct   = cl + 64;
    float* fbuf = cl + 96;            // 30*256

    // ---- convert ALL transformer weights once ----
    convert_w_all_kernel<<<21504, 256, 0, stream>>>(Wqkv, Wo, W1, W2, wall);

    // ---- patch embedding as MFMA GEMM ----
    convert_kernel<<<64, 256, 0, stream>>>(W_patch, wpb);
    patchify_kernel<<<NPAT, 256, 0, stream>>>(x, xnb);
    cls_pos_kernel<<<Bz, 256, 0, stream>>>(cls_tok, pos_emb, h0);
    gemm_s64<3><<<sg(98, 4), 256, 0, stream>>>(
        xnb, 256, wpb, 256, b_patch, h0, 256, 256, 98, 4, pos_emb);

    // ---- rag mixer (parallelized, fp32) ----
    means_kernel<<<Bz, 256, 0, stream>>>(h0, M);
    uvec_kernel<<<Bz, 256, 0, stream>>>(M, Wkl, bkl, Wkr, bkr, Wkt, bkt,
                                        Ul, Ur, Ut, cl, cr, ct);
    rag_score_kernel<<<(Bz - 2) * 4, 256, 0, stream>>>(
        h0, M, Ul, Ur, Ut, cl, cr, ct, Wvl, bvl, Wvr, bvr, Wvt, bvt, fbuf);
    rag_outer_kernel<<<(Bz - 2) * S, 256, 0, stream>>>(fbuf, M, h1);
    copy_edges<<<(2 * S * E + 255) / 256, 256, 0, stream>>>(h0, h1);

    for (int l = 0; l < Ln; l++) {
        const unsigned short* wqkv_b = wall + (size_t)l * WLSTRIDE;
        const unsigned short* wo_b   = wqkv_b + 196608;
        const unsigned short* w1_b   = wqkv_b + 262144;
        const unsigned short* w2_b   = wqkv_b + 1048576;
        ln_kernel<<<MS / 4, 256, 0, stream>>>(h1, xnb, ln1_g + l * E, ln1_b + l * E);
        gemm_s64<4><<<sg(100, 12), 256, 0, stream>>>(
            xnb, 256, wqkv_b, 256, bqkv + l * 768, qkb, 768, 256, 100, 12, nullptr);
        attn_kernel<<<Bz * Hn, 256, 0, stream>>>(qkb, ob);
        gemm_s64<1><<<sg(100, 4), 256, 0, stream>>>(
            ob, 256, wo_b, 256, bo + l * 256, h1, 256, 256, 100, 4, nullptr);
        ln_kernel<<<MS / 4, 256, 0, stream>>>(h1, xnb, ln2_g + l * E, ln2_b + l * E);
        gemm_s128<2><<<sg(50, 24), 256, 0, stream>>>(
            xnb, 256, w1_b, 256, b1 + l * Fd, ff, 3072, 256, 50, 24);
        gemm_s64<1><<<sg(100, 4), 256, 0, stream>>>(
            ff, 3072, w2_b, 3072, b2 + l * 256, h1, 256, 3072, 100, 4, nullptr);
    }
    head_kernel<<<Bz, 256, 0, stream>>>(h1, lnf_g, lnf_b, W_head, b_head, (float*)d_out);
}

// Round 10
// 1624.450 us; speedup vs baseline: 1.1657x; 1.0225x over previous
//
#include <hip/hip_runtime.h>
#include <hip/hip_bf16.h>
#include <math.h>

// Problem constants
constexpr int Bz  = 32;
constexpr int S   = 197;
constexpr int E   = 256;
constexpr int Hn  = 16;
constexpr int HD  = 16;
constexpr int Fd  = 3072;
constexpr int Ln  = 12;
constexpr int MS  = Bz * S;         // 6304 tokens
constexpr int MP  = 6400;           // padded: 100 m-tiles of 64 / 50 of 128
constexpr int NPAT = 6272;          // 32*196 patches = 98 * 64
constexpr int DVL = 50, DVR = 49, DVT = 49;
constexpr size_t WLSTRIDE = 1835008;  // bf16 weights per layer

typedef __attribute__((ext_vector_type(8))) short short8;   // 8 bf16 = 4 VGPRs
typedef __attribute__((ext_vector_type(4))) short short4v;
typedef __attribute__((ext_vector_type(4))) float f32x4;

__device__ __forceinline__ unsigned short f2bf(float f) {
    unsigned int u = __float_as_uint(f);
    u = (u + 0x7FFFu + ((u >> 16) & 1u)) >> 16;             // RNE
    return (unsigned short)u;
}

// async global->LDS, 16 B per lane. LDS dest is wave-uniform base + lane*16.
__device__ __forceinline__ void gload_lds16(const void* g, void* l) {
    __builtin_amdgcn_global_load_lds(
        (const __attribute__((address_space(1))) void*)g,
        (__attribute__((address_space(3))) void*)l, 16, 0, 0);
}

// wave reduce (64 lanes), op 0=sum 1=max
__device__ __forceinline__ float wave_reduce(float v, int op) {
    #pragma unroll
    for (int off = 32; off > 0; off >>= 1) {
        float o = __shfl_xor(v, off, 64);
        v = op ? fmaxf(v, o) : v + o;
    }
    return v;
}

// block-wide reduce (256 thr): wave shuffle + 4-slot LDS. op: 0=sum, 1=max.
__device__ __forceinline__ float block_reduce(float v, float* red4, int op) {
    v = wave_reduce(v, op);
    int w = threadIdx.x >> 6;
    if ((threadIdx.x & 63) == 0) red4[w] = v;
    __syncthreads();
    float r = op ? fmaxf(fmaxf(red4[0], red4[1]), fmaxf(red4[2], red4[3]))
                 : (red4[0] + red4[1] + red4[2] + red4[3]);
    __syncthreads();
    return r;
}

__device__ __forceinline__ float gelu_f(float v) {
    return 0.5f * v * (1.f + erff(v * 0.70710678118654752f));
}

// ---------------------------------------------------------------------------
// Patchify: x (B,1,224,224) -> bf16 A[6272][256], A[b*196+q][pr*16+pc].
__global__ __launch_bounds__(256) void patchify_kernel(
        const float* __restrict__ x, unsigned short* __restrict__ Ab) {
    int pi = blockIdx.x;                 // 0..6271
    int b = pi / 196, q = pi % 196;
    int i = q / 14, j = q % 14;
    int e = threadIdx.x, pr = e >> 4, pc = e & 15;
    float v = x[((size_t)(b * 224 + i * 16 + pr)) * 224 + j * 16 + pc];
    Ab[(size_t)pi * 256 + e] = f2bf(v);
}

// cls token rows of h0
__global__ __launch_bounds__(256) void cls_pos_kernel(
        const float* __restrict__ cls, const float* __restrict__ pos,
        float* __restrict__ h0) {
    int b = blockIdx.x, e = threadIdx.x;
    h0[(size_t)(b * S) * E + e] = cls[e] + pos[e];
}

// fp32 -> bf16, 4 elems/thread
__global__ __launch_bounds__(256) void convert_kernel(
        const float* __restrict__ src, unsigned short* __restrict__ dst) {
    int i4 = (blockIdx.x * 256 + threadIdx.x) * 4;
    float4 v = *(const float4*)(src + i4);
    ushort4 o;
    o.x = f2bf(v.x); o.y = f2bf(v.y); o.z = f2bf(v.z); o.w = f2bf(v.w);
    *(ushort4*)(dst + i4) = o;
}

// ALL layers' weights fp32 -> bf16 in one dispatch. grid 21504 x 256.
__global__ __launch_bounds__(256) void convert_w_all_kernel(
        const float* __restrict__ wqkv, const float* __restrict__ wo,
        const float* __restrict__ w1, const float* __restrict__ w2,
        unsigned short* __restrict__ out) {
    size_t idx = (size_t)blockIdx.x * 256 + threadIdx.x;   // 0..5505023
    int l = (int)(idx / 458752);
    int r4 = (int)(idx % 458752) * 4;
    const float* src;
    if (r4 < 196608)       src = wqkv + (size_t)l * 196608 + r4;
    else if (r4 < 262144)  src = wo   + (size_t)l * 65536  + (r4 - 196608);
    else if (r4 < 1048576) src = w1   + (size_t)l * 786432 + (r4 - 262144);
    else                   src = w2   + (size_t)l * 786432 + (r4 - 1048576);
    float4 v = *(const float4*)src;
    ushort4 o;
    o.x = f2bf(v.x); o.y = f2bf(v.y); o.z = f2bf(v.z); o.w = f2bf(v.w);
    *(ushort4*)(out + (size_t)l * WLSTRIDE + r4) = o;
}

// ---------------------------------------------------------------------------
// rag stage 1: per-sample token means. grid 32; waves split tokens (50 iters).
__global__ __launch_bounds__(256) void means_kernel(
        const float* __restrict__ h0, float* __restrict__ M) {
    __shared__ float part[4][256];
    int b = blockIdx.x, tid = threadIdx.x, w = tid >> 6, lane = tid & 63;
    float4 a = {0.f, 0.f, 0.f, 0.f};
    for (int t = w; t < S; t += 4) {
        float4 v = *(const float4*)&h0[((size_t)(b * S + t)) * E + lane * 4];
        a.x += v.x; a.y += v.y; a.z += v.z; a.w += v.w;
    }
    *(float4*)&part[w][lane * 4] = a;
    __syncthreads();
    M[b * E + tid] = (part[0][tid] + part[1][tid] + part[2][tid] + part[3][tid])
                     * (1.f / (float)S);
}

// rag stage 2: U_x[t] = Wk_x.T @ M[t], c_x[t] = bk_x . M[t]. grid 32.
__global__ __launch_bounds__(256) void uvec_kernel(
        const float* __restrict__ M,
        const float* __restrict__ Wkl, const float* __restrict__ bkl,
        const float* __restrict__ Wkr, const float* __restrict__ bkr,
        const float* __restrict__ Wkt, const float* __restrict__ bkt,
        float* __restrict__ Ul, float* __restrict__ Ur, float* __restrict__ Ut,
        float* __restrict__ cl, float* __restrict__ cr, float* __restrict__ ct) {
    __shared__ float p0[4][256], p1[4][256], p2[4][256], red4[4];
    int t = blockIdx.x, tid = threadIdx.x, w = tid >> 6, lane = tid & 63;
    const float* mt = M + t * E;
    float4 a0 = {0,0,0,0}, a1 = {0,0,0,0}, a2 = {0,0,0,0};
    for (int i = w * 64; i < w * 64 + 64; i++) {
        float mi = mt[i];
        float4 v0 = *(const float4*)&Wkl[(size_t)i * 256 + lane * 4];
        float4 v1 = *(const float4*)&Wkr[(size_t)i * 256 + lane * 4];
        float4 v2 = *(const float4*)&Wkt[(size_t)i * 256 + lane * 4];
        a0.x += v0.x * mi; a0.y += v0.y * mi; a0.z += v0.z * mi; a0.w += v0.w * mi;
        a1.x += v1.x * mi; a1.y += v1.y * mi; a1.z += v1.z * mi; a1.w += v1.w * mi;
        a2.x += v2.x * mi; a2.y += v2.y * mi; a2.z += v2.z * mi; a2.w += v2.w * mi;
    }
    *(float4*)&p0[w][lane * 4] = a0;
    *(float4*)&p1[w][lane * 4] = a1;
    *(float4*)&p2[w][lane * 4] = a2;
    __syncthreads();
    Ul[t * E + tid] = p0[0][tid] + p0[1][tid] + p0[2][tid] + p0[3][tid];
    Ur[t * E + tid] = p1[0][tid] + p1[1][tid] + p1[2][tid] + p1[3][tid];
    Ut[t * E + tid] = p2[0][tid] + p2[1][tid] + p2[2][tid] + p2[3][tid];
    float me = mt[tid];
    float c0 = block_reduce(bkl[tid] * me, red4, 0);
    float c1 = block_reduce(bkr[tid] * me, red4, 0);
    float c2 = block_reduce(bkt[tid] * me, red4, 0);
    if (tid == 0) { cl[t] = c0; cr[t] = c1; ct[t] = c2; }
}

// rag stage 3: scores+softmax+xbar+f for one (t, branch). grid 120, 256 thr.
__global__ __launch_bounds__(256) void rag_score_kernel(
        const float* __restrict__ h0, const float* __restrict__ M,
        const float* __restrict__ Ul, const float* __restrict__ Ur,
        const float* __restrict__ Ut,
        const float* __restrict__ cl, const float* __restrict__ cr,
        const float* __restrict__ ct,
        const float* __restrict__ Wvl, const float* __restrict__ bvl,
        const float* __restrict__ Wvr, const float* __restrict__ bvr,
        const float* __restrict__ Wvt, const float* __restrict__ bvt,
        float* __restrict__ fbuf) {
    int t = blockIdx.x >> 2, br = blockIdx.x & 3;
    const float* xsrc; const float* u; float c;
    const float* Wv; const float* bv; int dv, fo;
    if (br == 0)      { xsrc = h0 + (size_t)t * S * E;       u = Ul + (t+1)*E; c = cl[t+1]; Wv = Wvl; bv = bvl; dv = DVL; fo = 0; }
    else if (br == 1) { xsrc = h0 + (size_t)(t+1) * S * E;   u = Ut + t*E;     c = ct[t];   Wv = Wvt; bv = bvt; dv = DVT; fo = DVL; }
    else if (br == 2) { xsrc = h0 + (size_t)(t+1) * S * E;   u = Ut + (t+2)*E; c = ct[t+2]; Wv = Wvt; bv = bvt; dv = DVT; fo = DVL + DVT; }
    else              { xsrc = h0 + (size_t)(t+2) * S * E;   u = Ur + (t+1)*E; c = cr[t+1]; Wv = Wvr; bv = bvr; dv = DVR; fo = DVL + 2*DVT; }
    __shared__ float us[256], sc[200], xbar[256], part[4][256], red4[4];
    int tid = threadIdx.x, w = tid >> 6, lane = tid & 63;
    us[tid] = u[tid];
    __syncthreads();
    float4 u4 = *(float4*)&us[lane * 4];
    for (int s = w; s < S; s += 4) {
        float4 x4 = *(const float4*)&xsrc[(size_t)s * E + lane * 4];
        float p = x4.x*u4.x + x4.y*u4.y + x4.z*u4.z + x4.w*u4.w;
        p = wave_reduce(p, 0);
        if (lane == 0) sc[s] = (p + c) * 0.0625f;     // 1/sqrt(E)
    }
    __syncthreads();
    float v = (tid < S) ? sc[tid] : -1e30f;
    float mx = block_reduce(v, red4, 1);
    float ex = (tid < S) ? expf(v - mx) : 0.f;
    float dn = block_reduce(ex, red4, 0);
    if (tid < S) sc[tid] = ex / dn;
    __syncthreads();
    float4 pa = {0.f, 0.f, 0.f, 0.f};
    for (int s = w; s < S; s += 4) {
        float a = sc[s];
        float4 x4 = *(const float4*)&xsrc[(size_t)s * E + lane * 4];
        pa.x += a * x4.x; pa.y += a * x4.y; pa.z += a * x4.z; pa.w += a * x4.w;
    }
    *(float4*)&part[w][lane * 4] = pa;
    __syncthreads();
    xbar[tid] = part[0][tid] + part[1][tid] + part[2][tid] + part[3][tid];
    __syncthreads();
    float4 xb4 = *(float4*)&xbar[lane * 4];
    for (int d = w; d < dv; d += 4) {
        float4 w4 = *(const float4*)&Wv[(size_t)d * E + lane * 4];
        float p = w4.x*xb4.x + w4.y*xb4.y + w4.z*xb4.z + w4.w*xb4.w;
        p = wave_reduce(p, 0);
        if (lane == 0) fbuf[t * 256 + fo + d] = p + bv[d];
    }
}

// rag stage 4: outer product h1[t+1][s][:] = f[t][s] * M[t+1][:]
__global__ __launch_bounds__(256) void rag_outer_kernel(
        const float* __restrict__ fbuf, const float* __restrict__ M,
        float* __restrict__ h1) {
    int bid = blockIdx.x;                    // 0..30*197-1
    int t = bid / S, s = bid % S;
    float f = fbuf[t * 256 + s];             // uniform
    int e = threadIdx.x;
    h1[((size_t)((t + 1) * S + s)) * E + e] = f * M[(t + 1) * E + e];
}

// copy h0 samples 0 and 31 into h1
__global__ __launch_bounds__(256) void copy_edges(const float* __restrict__ h0,
                                                  float* __restrict__ h1) {
    int i = blockIdx.x * 256 + threadIdx.x;
    int n = S * E;
    if (i < n) h1[i] = h0[i];
    else if (i < 2 * n) {
        int j = i - n;
        size_t o = (size_t)31 * S * E + j;
        h1[o] = h0[o];
    }
}

// ---------------------------------------------------------------------------
// LayerNorm over E=256: wave per token, float4, shuffle-only. grid MS/4.
__global__ __launch_bounds__(256) void ln_kernel(const float* __restrict__ in,
                                                 unsigned short* __restrict__ out,
                                                 const float* __restrict__ g,
                                                 const float* __restrict__ b) {
    int w = threadIdx.x >> 6, lane = threadIdx.x & 63;
    int tok = blockIdx.x * 4 + w;
    const float* row = in + (size_t)tok * E;
    float4 v = *(const float4*)&row[lane * 4];
    float mean = wave_reduce(v.x + v.y + v.z + v.w, 0) * (1.f / 256.f);
    float dx = v.x - mean, dy = v.y - mean, dz = v.z - mean, dw = v.w - mean;
    float var = wave_reduce(dx*dx + dy*dy + dz*dz + dw*dw, 0) * (1.f / 256.f);
    float inv = rsqrtf(var + 1e-5f);
    float4 gg = *(const float4*)&g[lane * 4];
    float4 bb = *(const float4*)&b[lane * 4];
    ushort4 o;
    o.x = f2bf(dx * inv * gg.x + bb.x);
    o.y = f2bf(dy * inv * gg.y + bb.y);
    o.z = f2bf(dz * inv * gg.z + bb.z);
    o.w = f2bf(dw * inv * gg.w + bb.w);
    *(ushort4*)&out[(size_t)tok * E + lane * 4] = o;
}

// ---------------------------------------------------------------------------
// 64x64-tile bf16 MFMA GEMM. BK=64, double-buffered (32 KB LDS), XCD-swizzled
// flat grid: mt=(id&7)+8*(id/(8*NT)), nt=(id>>3)%NT. Blocks mt>=MT exit.
// MODE 1: fp32 += (+bias) | MODE 3: patch epilogue | MODE 4: bf16 store.
// MODE 4 uses SWAPPED mfma operands (D row index = n): each lane holds 4
// consecutive n per quad -> pack ushort4 -> per-wave LDS transpose -> fully
// coalesced 16B global stores (fixes the 1.7x HBM write amplification seen
// in r9: scattered 2B bf16 stores -> partial 64B lines).
template <int MODE>
__global__ __launch_bounds__(256) void gemm_s64(
        const unsigned short* __restrict__ A, int lda,
        const unsigned short* __restrict__ W, int ldw,
        const float* __restrict__ bias,
        void* __restrict__ Cv, int ldc, int K, int MT, int NT,
        const float* __restrict__ pos) {
    constexpr bool SWAP = (MODE == 4);
    __shared__ unsigned short As[2 * 64 * 64];
    __shared__ unsigned short Bs[2 * 64 * 64];
    const int id = blockIdx.x;
    const int mt = (id & 7) + 8 * (id / (8 * NT));
    const int nt = (id >> 3) % NT;
    if (mt >= MT) return;
    const int m0 = mt * 64, n0 = nt * 64;
    const int tid = threadIdx.x, wave = tid >> 6, lane = tid & 63;
    const int lr = lane & 15, kg = lane >> 4;
    const int srow = wave * 16 + (lane >> 3);           // +q*8
    const int scol = ((lane & 7) ^ (lane >> 3)) * 8;    // swizzled granule col
    auto stage = [&](int bb, int k0) {
        #pragma unroll
        for (int q = 0; q < 2; q++) {
            gload_lds16(&A[(size_t)(m0 + srow + q * 8) * lda + k0 + scol],
                        &As[bb * 4096 + (wave * 16 + q * 8) * 64]);
            gload_lds16(&W[(size_t)(n0 + srow + q * 8) * ldw + k0 + scol],
                        &Bs[bb * 4096 + (wave * 16 + q * 8) * 64]);
        }
    };
    const int nIter = K >> 6;
    stage(0, 0);
    f32x4 acc[4] = {};
    for (int i = 0; i < nIter; i++) {
        __syncthreads();
        if (i + 1 < nIter) stage((i + 1) & 1, (i + 1) * 64);
        const int bb = i & 1;
        #pragma unroll
        for (int h = 0; h < 2; h++) {
            const int sw = ((h * 4 + kg) ^ (lr & 7)) * 8;
            short8 af = *(short8*)&As[bb * 4096 + (wave * 16 + lr) * 64 + sw];
            #pragma unroll
            for (int j = 0; j < 4; j++) {
                short8 bf = *(short8*)&Bs[bb * 4096 + (j * 16 + lr) * 64 + sw];
                if (SWAP)
                    acc[j] = __builtin_amdgcn_mfma_f32_16x16x32_bf16(bf, af, acc[j], 0, 0, 0);
                else
                    acc[j] = __builtin_amdgcn_mfma_f32_16x16x32_bf16(af, bf, acc[j], 0, 0, 0);
            }
        }
    }
    if (SWAP) {
        // m = m0 + wave*16 + lr ; n = n0 + j*16 + kg*4 + r (4 consecutive)
        __syncthreads();                       // protect As reuse
        unsigned short* T = As + wave * 1152;  // 16 rows x stride 72
        #pragma unroll
        for (int j = 0; j < 4; j++) {
            int nb = n0 + j * 16 + kg * 4;
            float4 b4 = *(const float4*)&bias[nb];
            ushort4 pk;
            pk.x = f2bf(acc[j][0] + b4.x);
            pk.y = f2bf(acc[j][1] + b4.y);
            pk.z = f2bf(acc[j][2] + b4.z);
            pk.w = f2bf(acc[j][3] + b4.w);
            *(ushort4*)&T[lr * 72 + j * 16 + kg * 4] = pk;
        }
        int rrow = lane >> 3, cg = (lane & 7) * 8;
        #pragma unroll
        for (int g = 0; g < 2; g++) {
            int row = g * 8 + rrow;            // 0..15
            short8 val = *(short8*)&T[row * 72 + cg];
            int m = m0 + wave * 16 + row;
            *(short8*)&((unsigned short*)Cv)[(size_t)m * ldc + n0 + cg] = val;
        }
    } else {
        #pragma unroll
        for (int j = 0; j < 4; j++) {
            int n = n0 + j * 16 + lr;
            float bv = bias ? bias[n] : 0.f;
            #pragma unroll
            for (int r = 0; r < 4; r++) {
                int m = m0 + wave * 16 + kg * 4 + r;
                float v = acc[j][r] + bv;
                if (MODE == 1) ((float*)Cv)[(size_t)m * ldc + n] += v;
                if (MODE == 3) {
                    int b = m / 196, s = m - b * 196 + 1;   // token remap
                    ((float*)Cv)[((size_t)(b * S + s)) * E + n] = v + pos[(size_t)s * E + n];
                }
            }
        }
    }
}

// ---------------------------------------------------------------------------
// 128x128-tile bf16 MFMA GEMM, BK=64, double-buffered (64 KB LDS), XCD-
// swizzled flat grid. 4 waves x (64x64). MODE 2: gelu -> bf16 store with
// SWAPPED operands + LDS-transpose coalesced store epilogue (see gemm_s64).
template <int MODE>
__global__ __launch_bounds__(256) void gemm_s128(
        const unsigned short* __restrict__ A, int lda,
        const unsigned short* __restrict__ W, int ldw,
        const float* __restrict__ bias,
        void* __restrict__ Cv, int ldc, int K, int MT, int NT) {
    __shared__ unsigned short As[2 * 128 * 64];
    __shared__ unsigned short Bs[2 * 128 * 64];
    const int id = blockIdx.x;
    const int mt = (id & 7) + 8 * (id / (8 * NT));
    const int nt = (id >> 3) % NT;
    if (mt >= MT) return;
    const int m0 = mt * 128, n0 = nt * 128;
    const int tid = threadIdx.x, wave = tid >> 6, lane = tid & 63;
    const int wm = (wave >> 1) * 64, wn = (wave & 1) * 64;
    const int lr = lane & 15, kg = lane >> 4;
    const int srow = wave * 32 + (lane >> 3);
    const int scol = ((lane & 7) ^ (lane >> 3)) * 8;
    auto stage = [&](int bb, int k0) {
        #pragma unroll
        for (int q = 0; q < 4; q++) {
            gload_lds16(&A[(size_t)(m0 + srow + q * 8) * lda + k0 + scol],
                        &As[bb * 8192 + (wave * 4 + q) * 512]);
            gload_lds16(&W[(size_t)(n0 + srow + q * 8) * ldw + k0 + scol],
                        &Bs[bb * 8192 + (wave * 4 + q) * 512]);
        }
    };
    const int nIter = K >> 6;
    stage(0, 0);
    f32x4 acc[4][4] = {};
    for (int i = 0; i < nIter; i++) {
        __syncthreads();
        if (i + 1 < nIter) stage((i + 1) & 1, (i + 1) * 64);
        const int bb = i & 1;
        #pragma unroll
        for (int h = 0; h < 2; h++) {
            const int sw = ((h * 4 + kg) ^ (lr & 7)) * 8;
            short8 af[4], bfr[4];
            #pragma unroll
            for (int i2 = 0; i2 < 4; i2++) af[i2]  = *(short8*)&As[bb * 8192 + (wm + i2 * 16 + lr) * 64 + sw];
            #pragma unroll
            for (int j = 0; j < 4; j++) bfr[j] = *(short8*)&Bs[bb * 8192 + (wn + j * 16 + lr) * 64 + sw];
            #pragma unroll
            for (int i2 = 0; i2 < 4; i2++)
                #pragma unroll
                for (int j = 0; j < 4; j++)
                    // SWAPPED: D row = n (first operand), col = m
                    acc[i2][j] = __builtin_amdgcn_mfma_f32_16x16x32_bf16(bfr[j], af[i2], acc[i2][j], 0, 0, 0);
        }
    }
    // epilogue: m = m0+wm+i*16+lr ; n = n0+wn+j*16+kg*4+r (4 consecutive)
    __syncthreads();                         // protect As reuse
    unsigned short* T = As + wave * 2304;    // 32 rows x stride 72 per pass
    #pragma unroll
    for (int half = 0; half < 2; half++) {
        #pragma unroll
        for (int ii = 0; ii < 2; ii++) {
            int i = half * 2 + ii;
            #pragma unroll
            for (int j = 0; j < 4; j++) {
                int nb = n0 + wn + j * 16 + kg * 4;
                float4 b4 = *(const float4*)&bias[nb];
                ushort4 pk;
                pk.x = f2bf(gelu_f(acc[i][j][0] + b4.x));
                pk.y = f2bf(gelu_f(acc[i][j][1] + b4.y));
                pk.z = f2bf(gelu_f(acc[i][j][2] + b4.z));
                pk.w = f2bf(gelu_f(acc[i][j][3] + b4.w));
                *(ushort4*)&T[(ii * 16 + lr) * 72 + j * 16 + kg * 4] = pk;
            }
        }
        int rrow = lane >> 3, cg = (lane & 7) * 8;
        #pragma unroll
        for (int g = 0; g < 4; g++) {
            int row = g * 8 + rrow;          // 0..31
            short8 val = *(short8*)&T[row * 72 + cg];
            int m = m0 + wm + half * 32 + row;
            *(short8*)&((unsigned short*)Cv)[(size_t)m * ldc + n0 + wn + cg] = val;
        }
        if (half == 0) __syncthreads();
    }
}

static inline int sg(int MT, int NT) { return ((MT + 7) / 8) * 8 * NT; }

// ---------------------------------------------------------------------------
// MFMA flash attention. One block per (b,h); 4 waves, each takes Q-tiles
// round-robin. qkv bf16 [MS][768]; out bf16 [MS][256].
__global__ __launch_bounds__(256) void attn_kernel(
        const unsigned short* __restrict__ qkv, unsigned short* __restrict__ o) {
    int b = blockIdx.x >> 4, hh = blockIdx.x & 15;
    __shared__ unsigned short Qs[208][32];
    __shared__ unsigned short Ks[208][32];
    __shared__ unsigned short Vt[16][224];
    __shared__ unsigned short Ps[4][16][224];
    int tid = threadIdx.x, wave = tid >> 6, lane = tid & 63;
    int lr = lane & 15, kg = lane >> 4;
    short8 z8 = {};
    if (tid < 208) {
        if (tid < 197) {
            size_t row = (size_t)(b * S + tid) * 768 + hh * 16;
            *(short8*)&Qs[tid][0] = *(const short8*)&qkv[row];
            *(short8*)&Qs[tid][8] = *(const short8*)&qkv[row + 8];
            *(short8*)&Ks[tid][0] = *(const short8*)&qkv[row + 256];
            *(short8*)&Ks[tid][8] = *(const short8*)&qkv[row + 264];
            union { short8 v8[2]; unsigned short u[16]; } vv;
            vv.v8[0] = *(const short8*)&qkv[row + 512];
            vv.v8[1] = *(const short8*)&qkv[row + 520];
            #pragma unroll
            for (int d = 0; d < 16; d++) Vt[d][tid] = vv.u[d];
        } else {
            *(short8*)&Qs[tid][0] = z8; *(short8*)&Qs[tid][8] = z8;
            *(short8*)&Ks[tid][0] = z8; *(short8*)&Ks[tid][8] = z8;
            #pragma unroll
            for (int d = 0; d < 16; d++) Vt[d][tid] = 0;
        }
        *(short8*)&Qs[tid][16] = z8; *(short8*)&Qs[tid][24] = z8;
        *(short8*)&Ks[tid][16] = z8; *(short8*)&Ks[tid][24] = z8;
    } else if (tid < 224) {
        #pragma unroll
        for (int d = 0; d < 16; d++) Vt[d][tid] = 0;
    }
    {   // zero P pad cols [208,224) of this wave's scratch
        short4v z4 = {};
        *(short4v*)&Ps[wave][lane >> 2][208 + (lane & 3) * 4] = z4;
    }
    __syncthreads();
    const f32x4 zf = {0.f, 0.f, 0.f, 0.f};
    for (int it = wave; it < 13; it += 4) {
        short8 qa = *(short8*)&Qs[it * 16 + lr][kg * 8];
        f32x4 sc[13];
        #pragma unroll
        for (int j = 0; j < 13; j++) {
            short8 kb = *(short8*)&Ks[j * 16 + lr][kg * 8];
            sc[j] = __builtin_amdgcn_mfma_f32_16x16x32_bf16(qa, kb, zf, 0, 0, 0);
        }
        float m[4] = {-1e30f, -1e30f, -1e30f, -1e30f};
        #pragma unroll
        for (int j = 0; j < 13; j++) {
            if (j * 16 + lr < 197) {
                #pragma unroll
                for (int r = 0; r < 4; r++) m[r] = fmaxf(m[r], sc[j][r]);
            }
        }
        #pragma unroll
        for (int off = 1; off < 16; off <<= 1)
            #pragma unroll
            for (int r = 0; r < 4; r++) m[r] = fmaxf(m[r], __shfl_xor(m[r], off, 64));
        float l[4] = {0.f, 0.f, 0.f, 0.f};
        #pragma unroll
        for (int j = 0; j < 13; j++) {
            bool valid = (j * 16 + lr) < 197;
            #pragma unroll
            for (int r = 0; r < 4; r++) {
                float p = valid ? __expf((sc[j][r] - m[r]) * 0.25f) : 0.f;
                l[r] += p;
                Ps[wave][kg * 4 + r][j * 16 + lr] = f2bf(p);
            }
        }
        #pragma unroll
        for (int off = 1; off < 16; off <<= 1)
            #pragma unroll
            for (int r = 0; r < 4; r++) l[r] += __shfl_xor(l[r], off, 64);
        f32x4 oa = zf;
        #pragma unroll
        for (int k0 = 0; k0 < 224; k0 += 32) {
            short8 pa = *(short8*)&Ps[wave][lr][k0 + kg * 8];
            short8 vb = *(short8*)&Vt[lr][k0 + kg * 8];
            oa = __builtin_amdgcn_mfma_f32_16x16x32_bf16(pa, vb, oa, 0, 0, 0);
        }
        #pragma unroll
        for (int r = 0; r < 4; r++) {
            int q = it * 16 + kg * 4 + r;
            if (q < 197)
                o[((size_t)(b * S + q)) * 256 + hh * 16 + lr] = f2bf(oa[r] / l[r]);
        }
    }
}

// ---------------------------------------------------------------------------
// Final LN on cls token + head GEMM. One block per sample.
__global__ __launch_bounds__(256) void head_kernel(
        const float* __restrict__ h, const float* __restrict__ g,
        const float* __restrict__ bb, const float* __restrict__ Wh,
        const float* __restrict__ bh, float* __restrict__ out) {
    __shared__ float red4[4];
    __shared__ float xs[256];
    int b = blockIdx.x, e = threadIdx.x;
    float v = h[((size_t)(b * S)) * E + e];
    float mean = block_reduce(v, red4, 0) * (1.f / 256.f);
    float d = v - mean;
    float var = block_reduce(d * d, red4, 0) * (1.f / 256.f);
    float xn = d * rsqrtf(var + 1e-5f) * g[e] + bb[e];
    xs[e] = xn;
    __syncthreads();
    for (int n = 0; n < 8; n++) {
        float s = block_reduce(xs[e] * Wh[(size_t)n * 256 + e], red4, 0);
        if (e == 0) out[b * 8 + n] = s + bh[n];
    }
}

// ---------------------------------------------------------------------------
extern "C" void kernel_launch(void* const* d_in, const int* in_sizes, int n_in,
                              void* d_out, int out_size, void* d_ws, size_t ws_size,
                              hipStream_t stream) {
    const float* x      = (const float*)d_in[0];
    const float* W_patch= (const float*)d_in[1];
    const float* b_patch= (const float*)d_in[2];
    const float* cls_tok= (const float*)d_in[3];
    const float* pos_emb= (const float*)d_in[4];
    const float* Wkl = (const float*)d_in[5];   const float* bkl = (const float*)d_in[6];
    const float* Wvl = (const float*)d_in[7];   const float* bvl = (const float*)d_in[8];
    const float* Wkr = (const float*)d_in[9];   const float* bkr = (const float*)d_in[10];
    const float* Wvr = (const float*)d_in[11];  const float* bvr = (const float*)d_in[12];
    const float* Wkt = (const float*)d_in[13];  const float* bkt = (const float*)d_in[14];
    const float* Wvt = (const float*)d_in[15];  const float* bvt = (const float*)d_in[16];
    const float* ln1_g = (const float*)d_in[17]; const float* ln1_b = (const float*)d_in[18];
    const float* Wqkv  = (const float*)d_in[19]; const float* bqkv  = (const float*)d_in[20];
    const float* Wo    = (const float*)d_in[21]; const float* bo    = (const float*)d_in[22];
    const float* ln2_g = (const float*)d_in[23]; const float* ln2_b = (const float*)d_in[24];
    const float* W1 = (const float*)d_in[25];   const float* b1 = (const float*)d_in[26];
    const float* W2 = (const float*)d_in[27];   const float* b2 = (const float*)d_in[28];
    const float* lnf_g = (const float*)d_in[29]; const float* lnf_b = (const float*)d_in[30];
    const float* W_head = (const float*)d_in[31]; const float* b_head = (const float*)d_in[32];

    // Workspace layout — ws_size is 256 MiB; no aliasing. Total ~113 MB.
    char* p = (char*)d_ws;
    float* h0 = (float*)p;                    p += (size_t)MP * 256 * 4;
    float* h1 = (float*)p;                    p += (size_t)MP * 256 * 4;
    unsigned short* qkb = (unsigned short*)p; p += (size_t)MP * 768 * 2;
    unsigned short* xnb = (unsigned short*)p; p += (size_t)MP * 256 * 2;
    unsigned short* ob  = (unsigned short*)p; p += (size_t)MP * 256 * 2;
    unsigned short* ff  = (unsigned short*)p; p += (size_t)MP * 3072 * 2;
    unsigned short* wpb = (unsigned short*)p; p += (size_t)65536 * 2;
    float* ragws = (float*)p;                 p += (size_t)40960 * 4;
    unsigned short* wall = (unsigned short*)p;
    float* M    = ragws;              // 32*256
    float* Ul   = ragws + 8192;
    float* Ur   = ragws + 2 * 8192;
    float* Ut   = ragws + 3 * 8192;
    float* cl   = ragws + 4 * 8192;   // 32
    float* cr   = cl + 32;
    float* ct   = cl + 64;
    float* fbuf = cl + 96;            // 30*256

    // ---- convert ALL transformer weights once ----
    convert_w_all_kernel<<<21504, 256, 0, stream>>>(Wqkv, Wo, W1, W2, wall);

    // ---- patch embedding as MFMA GEMM ----
    convert_kernel<<<64, 256, 0, stream>>>(W_patch, wpb);
    patchify_kernel<<<NPAT, 256, 0, stream>>>(x, xnb);
    cls_pos_kernel<<<Bz, 256, 0, stream>>>(cls_tok, pos_emb, h0);
    gemm_s64<3><<<sg(98, 4), 256, 0, stream>>>(
        xnb, 256, wpb, 256, b_patch, h0, 256, 256, 98, 4, pos_emb);

    // ---- rag mixer (parallelized, fp32) ----
    means_kernel<<<Bz, 256, 0, stream>>>(h0, M);
    uvec_kernel<<<Bz, 256, 0, stream>>>(M, Wkl, bkl, Wkr, bkr, Wkt, bkt,
                                        Ul, Ur, Ut, cl, cr, ct);
    rag_score_kernel<<<(Bz - 2) * 4, 256, 0, stream>>>(
        h0, M, Ul, Ur, Ut, cl, cr, ct, Wvl, bvl, Wvr, bvr, Wvt, bvt, fbuf);
    rag_outer_kernel<<<(Bz - 2) * S, 256, 0, stream>>>(fbuf, M, h1);
    copy_edges<<<(2 * S * E + 255) / 256, 256, 0, stream>>>(h0, h1);

    for (int l = 0; l < Ln; l++) {
        const unsigned short* wqkv_b = wall + (size_t)l * WLSTRIDE;
        const unsigned short* wo_b   = wqkv_b + 196608;
        const unsigned short* w1_b   = wqkv_b + 262144;
        const unsigned short* w2_b   = wqkv_b + 1048576;
        ln_kernel<<<MS / 4, 256, 0, stream>>>(h1, xnb, ln1_g + l * E, ln1_b + l * E);
        gemm_s64<4><<<sg(100, 12), 256, 0, stream>>>(
            xnb, 256, wqkv_b, 256, bqkv + l * 768, qkb, 768, 256, 100, 12, nullptr);
        attn_kernel<<<Bz * Hn, 256, 0, stream>>>(qkb, ob);
        gemm_s64<1><<<sg(100, 4), 256, 0, stream>>>(
            ob, 256, wo_b, 256, bo + l * 256, h1, 256, 256, 100, 4, nullptr);
        ln_kernel<<<MS / 4, 256, 0, stream>>>(h1, xnb, ln2_g + l * E, ln2_b + l * E);
        gemm_s128<2><<<sg(50, 24), 256, 0, stream>>>(
            xnb, 256, w1_b, 256, b1 + l * Fd, ff, 3072, 256, 50, 24);
        gemm_s64<1><<<sg(100, 4), 256, 0, stream>>>(
            ff, 3072, w2_b, 3072, b2 + l * 256, h1, 256, 3072, 100, 4, nullptr);
    }
    head_kernel<<<Bz, 256, 0, stream>>>(h1, lnf_g, lnf_b, W_head, b_head, (float*)d_out);
}